// Round 3
// baseline (4754.914 us; speedup 1.0000x reference)
//
#include <hip/hip_runtime.h>
#include <math.h>

#define D_MODEL 1024
#define D_STATE 16
#define D_CONV 4
#define D_INNER 2048
#define DT_RANK 64
#define BATCH 4
#define SEQ 2048
#define ML (BATCH * SEQ)  // 8192 rows

// ---------------------------------------------------------------------------
// dtype helpers: inputs may be fp32 (expected) or bf16 (detected at runtime).
// ---------------------------------------------------------------------------
__device__ __forceinline__ float bf2f(unsigned short u) {
  union { unsigned int i; float f; } v;
  v.i = ((unsigned int)u) << 16;
  return v.f;
}
__device__ __forceinline__ unsigned short f2bf(float f) {
  union { float f; unsigned int i; } u;
  u.f = f;
  unsigned int r = u.i + 0x7fffu + ((u.i >> 16) & 1u);  // RNE
  return (unsigned short)(r >> 16);
}
template <bool BF>
__device__ __forceinline__ float ld1(const void* p, size_t i) {
  if constexpr (BF) return bf2f(((const unsigned short*)p)[i]);
  else return ((const float*)p)[i];
}
template <bool BF>
__device__ __forceinline__ void ld4(const void* p, size_t i, float o[4]) {
  if constexpr (BF) {
    ushort4 v = *(const ushort4*)((const unsigned short*)p + i);
    o[0] = bf2f(v.x); o[1] = bf2f(v.y); o[2] = bf2f(v.z); o[3] = bf2f(v.w);
  } else {
    float4 v = *(const float4*)((const float*)p + i);
    o[0] = v.x; o[1] = v.y; o[2] = v.z; o[3] = v.w;
  }
}
template <bool BF>
__device__ __forceinline__ void st1(void* p, size_t i, float v) {
  if constexpr (BF) ((unsigned short*)p)[i] = f2bf(v);
  else ((float*)p)[i] = v;
}

// ---------------------------------------------------------------------------
// Runtime dtype detection. For bf16(N(0,1)) data, the low ushort of each
// 32-bit word is a bf16 sample whose exponent field (bits 14..7) lies in
// ~[103,141]. For fp32 data those bits are uniform mantissa bits -> ~82%
// fall outside [100,145]. flag=1 means bf16 inputs.
// ---------------------------------------------------------------------------
__global__ void detect_kernel(const unsigned int* __restrict__ xw, int* flag) {
  __shared__ int cnt;
  if (threadIdx.x == 0) cnt = 0;
  __syncthreads();
  unsigned int w = xw[threadIdx.x];
  unsigned int e = (w >> 7) & 0xffu;
  if (e < 100u || e > 145u) atomicAdd(&cnt, 1);
  __syncthreads();
  if (threadIdx.x == 0) flag[0] = (cnt < 32) ? 1 : 0;
}

// ---------------------------------------------------------------------------
// C[M,N] = A[M,K] * B[N,K]^T  (row-major "NT"). BM=BN=64, BK=16, 256 thr,
// 4x4 micro-tile. Dtypes of A/B/C selected by template flags.
// ---------------------------------------------------------------------------
template <bool BFA, bool BFB, bool BFC>
__device__ __forceinline__ void gemm_body(const void* __restrict__ A,
                                          const void* __restrict__ B,
                                          void* __restrict__ C, int M, int N,
                                          int K, float (*As)[64],
                                          float (*Bs)[64]) {
  const int tid = threadIdx.x;
  const int bm = blockIdx.y * 64;
  const int bn = blockIdx.x * 64;
  const int lr = tid >> 2;        // 0..63 tile row
  const int lc = (tid & 3) << 2;  // 0,4,8,12 k offset
  const int tx = tid & 15;
  const int ty = tid >> 4;
  float acc[4][4] = {{0.f}};
  const size_t aoff = (size_t)(bm + lr) * K + lc;
  const size_t boff = (size_t)(bn + lr) * K + lc;
  for (int k0 = 0; k0 < K; k0 += 16) {
    float av[4], bv[4];
    ld4<BFA>(A, aoff + k0, av);
    ld4<BFB>(B, boff + k0, bv);
#pragma unroll
    for (int i = 0; i < 4; ++i) As[lc + i][lr] = av[i];
#pragma unroll
    for (int i = 0; i < 4; ++i) Bs[lc + i][lr] = bv[i];
    __syncthreads();
#pragma unroll
    for (int kk = 0; kk < 16; ++kk) {
      float a[4], b[4];
#pragma unroll
      for (int i = 0; i < 4; ++i) a[i] = As[kk][ty * 4 + i];
#pragma unroll
      for (int j = 0; j < 4; ++j) b[j] = Bs[kk][tx * 4 + j];
#pragma unroll
      for (int i = 0; i < 4; ++i)
#pragma unroll
        for (int j = 0; j < 4; ++j) acc[i][j] += a[i] * b[j];
    }
    __syncthreads();
  }
#pragma unroll
  for (int i = 0; i < 4; ++i) {
    const size_t coff = (size_t)(bm + ty * 4 + i) * N + bn + tx * 4;
#pragma unroll
    for (int j = 0; j < 4; ++j) st1<BFC>(C, coff + j, acc[i][j]);
  }
}

// K1: xz = x @ in_proj_w^T ; A,B follow input dtype, C fp32.
__global__ __launch_bounds__(256) void gemm_k1(const void* __restrict__ A,
                                               const void* __restrict__ B,
                                               float* __restrict__ C, int M,
                                               int N, int K,
                                               const int* __restrict__ flag) {
  __shared__ float As[16][64];
  __shared__ float Bs[16][64];
  if (*flag) gemm_body<true, true, false>(A, B, C, M, N, K, As, Bs);
  else gemm_body<false, false, false>(A, B, C, M, N, K, As, Bs);
}

// K6: out = y @ out_proj_w^T ; A fp32 (ws), B input dtype, C output dtype.
__global__ __launch_bounds__(256) void gemm_k6(const float* __restrict__ A,
                                               const void* __restrict__ B,
                                               void* __restrict__ C, int M,
                                               int N, int K,
                                               const int* __restrict__ flag) {
  __shared__ float As[16][64];
  __shared__ float Bs[16][64];
  if (*flag) gemm_body<false, true, true>(A, B, C, M, N, K, As, Bs);
  else gemm_body<false, false, false>(A, B, C, M, N, K, As, Bs);
}

// ---------------------------------------------------------------------------
// Depthwise causal conv (width 4) + bias + SiLU. xz (ML,4096) fp32, x part
// cols [0,2048). Output xc (ML,2048) fp32.
// ---------------------------------------------------------------------------
__global__ __launch_bounds__(256) void conv_silu_kernel(
    const float* __restrict__ xz, const void* __restrict__ cw,
    const void* __restrict__ cb, float* __restrict__ xc,
    const int* __restrict__ flag) {
  const int bf = *flag;
  const int idx = blockIdx.x * 256 + threadIdx.x;  // over ML*D_INNER
  const int d = idx & (D_INNER - 1);
  const int bl = idx >> 11;
  const int l = bl & (SEQ - 1);
  float w[4];
  if (bf) ld4<true>(cw, (size_t)d * 4, w);
  else ld4<false>(cw, (size_t)d * 4, w);
  const float bias = bf ? ld1<true>(cb, d) : ld1<false>(cb, d);
  const size_t base = (size_t)bl * 4096 + d;
  float acc = bias + w[3] * xz[base];
  if (l >= 1) acc += w[2] * xz[base - 4096];
  if (l >= 2) acc += w[1] * xz[base - 2 * 4096];
  if (l >= 3) acc += w[0] * xz[base - 3 * 4096];
  xc[idx] = acc / (1.f + __expf(-acc));  // silu
}

// ---------------------------------------------------------------------------
// dbl[m,e] = dot(xc[m,:], x_proj_w[e,:]), e < 96, K = 2048.
// ---------------------------------------------------------------------------
template <bool BF>
__device__ __forceinline__ void xproj_body(const float* __restrict__ xc,
                                           const void* __restrict__ W,
                                           float* __restrict__ dbl) {
  const int e = threadIdx.x;  // 0..95
  const int m = blockIdx.x * blockDim.y + threadIdx.y;
  const float* xr = xc + (size_t)m * D_INNER;
  const size_t woff = (size_t)e * D_INNER;
  float acc = 0.f;
#pragma unroll 4
  for (int k = 0; k < D_INNER; k += 4) {
    float a[4], b[4];
    ld4<false>(xr, k, a);
    ld4<BF>(W, woff + k, b);
    acc += a[0] * b[0] + a[1] * b[1] + a[2] * b[2] + a[3] * b[3];
  }
  dbl[(size_t)m * 96 + e] = acc;
}
__global__ void xproj_kernel(const float* __restrict__ xc,
                             const void* __restrict__ W,
                             float* __restrict__ dbl,
                             const int* __restrict__ flag) {
  if (*flag) xproj_body<true>(xc, W, dbl);
  else xproj_body<false>(xc, W, dbl);
}

// ---------------------------------------------------------------------------
// dt = softplus(dbl[:, :64] @ dt_proj_w^T + b) -> xz cols [0,2048)
// (x half of xz is dead after conv).
// ---------------------------------------------------------------------------
template <bool BF>
__device__ __forceinline__ void dtproj_body(const float* __restrict__ dbl,
                                            const void* __restrict__ W,
                                            const void* __restrict__ bias,
                                            float* __restrict__ xzdt) {
  const int idx = blockIdx.x * 256 + threadIdx.x;  // over ML*D_INNER
  const int d = idx & (D_INNER - 1);
  const int m = idx >> 11;
  const float* xr = dbl + (size_t)m * 96;  // dt_x = first 64 cols
  const size_t woff = (size_t)d * DT_RANK;
  float acc = ld1<BF>(bias, d);
#pragma unroll
  for (int k = 0; k < DT_RANK; k += 4) {
    float a[4], b[4];
    ld4<false>(xr, k, a);
    ld4<BF>(W, woff + k, b);
    acc += a[0] * b[0] + a[1] * b[1] + a[2] * b[2] + a[3] * b[3];
  }
  xzdt[(size_t)m * 4096 + d] = (acc > 20.f) ? acc : log1pf(expf(acc));
}
__global__ __launch_bounds__(256) void dtproj_kernel(
    const float* __restrict__ dbl, const void* __restrict__ W,
    const void* __restrict__ bias, float* __restrict__ xzdt,
    const int* __restrict__ flag) {
  if (*flag) dtproj_body<true>(dbl, W, bias, xzdt);
  else dtproj_body<false>(dbl, W, bias, xzdt);
}

// ---------------------------------------------------------------------------
// Selective scan. 16 lanes per (b,d) sequence, lane = state index n.
// h_t = exp(dt*A[d,n]) * h_{t-1} + dt*B_t[n]*x_t ; y_t = sum_n h*C_t[n].
// Fused epilogue: y = (y + D*x) * silu(z), written in-place over xc.
// ---------------------------------------------------------------------------
__global__ __launch_bounds__(256) void scan_kernel(
    const float* __restrict__ xzdt, const float* __restrict__ dbl,
    const void* __restrict__ A_log, const void* __restrict__ Dp,
    float* __restrict__ xc, const int* __restrict__ flag) {
  const int bf = *flag;
  const int tid = threadIdx.x;
  const int n = tid & 15;
  const int g = tid >> 4;              // group within block
  const int gd = blockIdx.x * 16 + g;  // sequence id: b*D_INNER + d
  const int b = gd >> 11;
  const int d = gd & (D_INNER - 1);
  const float alog = bf ? ld1<true>(A_log, d * D_STATE + n)
                        : ld1<false>(A_log, d * D_STATE + n);
  const float a = -expf(alog);
  const float Dv = bf ? ld1<true>(Dp, d) : ld1<false>(Dp, d);
  float h = 0.f;
  const float* dt_p = xzdt + (size_t)b * SEQ * 4096 + d;
  const float* z_p = dt_p + D_INNER;
  float* x_p = xc + (size_t)b * SEQ * D_INNER + d;  // read x, write y
  const float* bc_p = dbl + (size_t)b * SEQ * 96 + DT_RANK + n;
#pragma unroll 4
  for (int t = 0; t < SEQ; ++t) {
    const float dtv = dt_p[(size_t)t * 4096];
    const float xv = x_p[(size_t)t * D_INNER];
    const float Bv = bc_p[(size_t)t * 96];
    const float Cv = bc_p[(size_t)t * 96 + D_STATE];
    const float dA = __expf(dtv * a);
    h = dA * h + dtv * Bv * xv;
    float p = h * Cv;
    p += __shfl_xor(p, 1);
    p += __shfl_xor(p, 2);
    p += __shfl_xor(p, 4);
    p += __shfl_xor(p, 8);
    if (n == 0) {
      const float zv = z_p[(size_t)t * 4096];
      const float yv = p + Dv * xv;
      x_p[(size_t)t * D_INNER] = yv * (zv / (1.f + __expf(-zv)));
    }
  }
}

// ---------------------------------------------------------------------------
extern "C" void kernel_launch(void* const* d_in, const int* in_sizes, int n_in,
                              void* d_out, int out_size, void* d_ws,
                              size_t ws_size, hipStream_t stream) {
  const void* x = d_in[0];
  const void* in_proj_w = d_in[1];
  const void* conv_w = d_in[2];
  const void* conv_b = d_in[3];
  const void* x_proj_w = d_in[4];
  const void* dt_proj_w = d_in[5];
  const void* dt_proj_b = d_in[6];
  const void* A_log = d_in[7];
  const void* D_param = d_in[8];
  const void* out_proj_w = d_in[9];

  // ws layout: [flag pad 256B] xz (ML x 4096 f32) | xc (ML x 2048 f32) |
  //            dbl (ML x 96 f32)   -- total ~204.5 MB
  int* flag = (int*)d_ws;
  float* xz = (float*)d_ws + 64;
  float* xc = xz + (size_t)ML * 4096;
  float* dbl = xc + (size_t)ML * D_INNER;

  // K0: detect input dtype (fp32 vs bf16) from x's bit patterns.
  detect_kernel<<<1, 256, 0, stream>>>((const unsigned int*)x, flag);
  // K1: xz = x @ in_proj_w^T   (M=8192, N=4096, K=1024)
  {
    dim3 g(4096 / 64, ML / 64);
    gemm_k1<<<g, 256, 0, stream>>>(x, in_proj_w, xz, ML, 4096, 1024, flag);
  }
  // K2: causal depthwise conv + SiLU -> xc (fp32)
  conv_silu_kernel<<<(ML * D_INNER) / 256, 256, 0, stream>>>(xz, conv_w,
                                                             conv_b, xc, flag);
  // K3: dbl = xc @ x_proj_w^T  (N=96, K=2048)
  {
    dim3 blk(96, 4);
    xproj_kernel<<<ML / 4, blk, 0, stream>>>(xc, x_proj_w, dbl, flag);
  }
  // K4: dt = softplus(dbl[:, :64] @ dt_proj_w^T + b) -> xz cols [0,2048)
  dtproj_kernel<<<(ML * D_INNER) / 256, 256, 0, stream>>>(dbl, dt_proj_w,
                                                          dt_proj_b, xz, flag);
  // K5: selective scan (fuses +D*x and *silu(z)); y overwrites xc
  scan_kernel<<<(BATCH * D_INNER) / 16, 256, 0, stream>>>(xz, dbl, A_log,
                                                          D_param, xc, flag);
  // K6: out = y @ out_proj_w^T (M=8192, N=1024, K=2048)
  {
    dim3 g(1024 / 64, ML / 64);
    gemm_k6<<<g, 256, 0, stream>>>(xc, out_proj_w, d_out, ML, 1024, 2048,
                                   flag);
  }
}

// Round 4
// 2395.561 us; speedup vs baseline: 1.9849x; 1.9849x over previous
//
#include <hip/hip_runtime.h>
#include <math.h>

#define D_MODEL 1024
#define D_STATE 16
#define D_CONV 4
#define D_INNER 2048
#define DT_RANK 64
#define BATCH 4
#define SEQ 2048
#define ML (BATCH * SEQ)  // 8192 rows
#define NCH 8             // scan chunks per sequence
#define CL (SEQ / NCH)    // 256 steps per chunk

typedef __attribute__((ext_vector_type(8))) short short8;
typedef __attribute__((ext_vector_type(4))) float f32x4;

// ---------------------------------------------------------------------------
// dtype helpers: inputs may be fp32 (expected) or bf16 (runtime-detected).
// ---------------------------------------------------------------------------
__device__ __forceinline__ float bf2f(unsigned short u) {
  union { unsigned int i; float f; } v;
  v.i = ((unsigned int)u) << 16;
  return v.f;
}
__device__ __forceinline__ unsigned short f2bf(float f) {
  union { float f; unsigned int i; } u;
  u.f = f;
  unsigned int r = u.i + 0x7fffu + ((u.i >> 16) & 1u);  // RNE
  return (unsigned short)(r >> 16);
}
template <bool BF>
__device__ __forceinline__ float ld1(const void* p, size_t i) {
  if constexpr (BF) return bf2f(((const unsigned short*)p)[i]);
  else return ((const float*)p)[i];
}
template <bool BF>
__device__ __forceinline__ void ld4(const void* p, size_t i, float o[4]) {
  if constexpr (BF) {
    ushort4 v = *(const ushort4*)((const unsigned short*)p + i);
    o[0] = bf2f(v.x); o[1] = bf2f(v.y); o[2] = bf2f(v.z); o[3] = bf2f(v.w);
  } else {
    float4 v = *(const float4*)((const float*)p + i);
    o[0] = v.x; o[1] = v.y; o[2] = v.z; o[3] = v.w;
  }
}

// async global->LDS, 16 B per lane; lds base must be wave-uniform.
__device__ __forceinline__ void gl_lds16(const unsigned short* g,
                                         unsigned short* l) {
  __builtin_amdgcn_global_load_lds(
      (const __attribute__((address_space(1))) void*)g,
      (__attribute__((address_space(3))) void*)l, 16, 0, 0);
}

// ---------------------------------------------------------------------------
// Runtime dtype detection (see R2 notes): flag=1 means bf16 inputs.
// ---------------------------------------------------------------------------
__global__ void detect_kernel(const unsigned int* __restrict__ xw, int* flag) {
  __shared__ int cnt;
  if (threadIdx.x == 0) cnt = 0;
  __syncthreads();
  unsigned int w = xw[threadIdx.x];
  unsigned int e = (w >> 7) & 0xffu;
  if (e < 100u || e > 145u) atomicAdd(&cnt, 1);
  __syncthreads();
  if (threadIdx.x == 0) flag[0] = (cnt < 32) ? 1 : 0;
}

// ---------------------------------------------------------------------------
// fp32->bf16 conversion (or plain copy when inputs are already bf16).
// n multiple of 1024; one thread handles 4 elements.
// ---------------------------------------------------------------------------
__global__ __launch_bounds__(256) void cvt_kernel(const void* __restrict__ in,
                                                  unsigned short* __restrict__ out,
                                                  int n, const int* __restrict__ flag) {
  const int i = (blockIdx.x * 256 + threadIdx.x) * 4;
  if (i >= n) return;
  if (*flag) {
    *(ushort4*)(out + i) = *(const ushort4*)((const unsigned short*)in + i);
  } else {
    float4 v = *(const float4*)((const float*)in + i);
    ushort4 o;
    o.x = f2bf(v.x); o.y = f2bf(v.y); o.z = f2bf(v.z); o.w = f2bf(v.w);
    *(ushort4*)(out + i) = o;
  }
}

// ---------------------------------------------------------------------------
// MFMA bf16 GEMM: C[M,N] = A[M,K] * B[N,K]^T. A,B bf16 (ushort), row-major.
// 128x128 tile, BK=32, 256 threads = 4 waves (2x2), 64x64 per wave,
// 16x16x32 MFMA, global_load_lds width-16 staging (m97 structure).
// OUT_FLAG=false: C is bf16 (ushort). OUT_FLAG=true: C dtype per *flag.
// ---------------------------------------------------------------------------
template <bool OUT_FLAG>
__global__ __launch_bounds__(256) void gemm_mfma(
    const unsigned short* __restrict__ A, const unsigned short* __restrict__ B,
    void* __restrict__ C, int M, int N, int K, const int* __restrict__ flag) {
  __shared__ unsigned short As[128 * 32];
  __shared__ unsigned short Bs[128 * 32];
  const int tid = threadIdx.x;
  const int l = tid & 63, w = tid >> 6;
  const int bm = blockIdx.y * 128;
  const int bn = blockIdx.x * 128;
  // staging coords: lane l of wave w loads 16B = row (w*16 + l/4), col chunk l%4
  const int r0 = w * 16 + (l >> 2);
  const int cc = (l & 3) * 8;
  const unsigned short* Ap0 = A + (size_t)(bm + r0) * K + cc;
  const unsigned short* Ap1 = A + (size_t)(bm + r0 + 64) * K + cc;
  const unsigned short* Bp0 = B + (size_t)(bn + r0) * K + cc;
  const unsigned short* Bp1 = B + (size_t)(bn + r0 + 64) * K + cc;
  // fragment coords
  const int q = l >> 4, mr = l & 15;
  const int wm = w >> 1, wn = w & 1;
  f32x4 acc[4][4] = {};
  for (int k0 = 0; k0 < K; k0 += 32) {
    gl_lds16(Ap0 + k0, As + w * 512);
    gl_lds16(Ap1 + k0, As + 2048 + w * 512);
    gl_lds16(Bp0 + k0, Bs + w * 512);
    gl_lds16(Bp1 + k0, Bs + 2048 + w * 512);
    __syncthreads();  // drains vmcnt (global_load_lds) + lgkm
    short8 af[4], bfr[4];
#pragma unroll
    for (int mi = 0; mi < 4; ++mi)
      af[mi] = *(const short8*)&As[(wm * 64 + mi * 16 + mr) * 32 + q * 8];
#pragma unroll
    for (int ni = 0; ni < 4; ++ni)
      bfr[ni] = *(const short8*)&Bs[(wn * 64 + ni * 16 + mr) * 32 + q * 8];
#pragma unroll
    for (int mi = 0; mi < 4; ++mi)
#pragma unroll
      for (int ni = 0; ni < 4; ++ni)
        acc[mi][ni] = __builtin_amdgcn_mfma_f32_16x16x32_bf16(
            af[mi], bfr[ni], acc[mi][ni], 0, 0, 0);
    __syncthreads();
  }
  // epilogue: C/D layout col=lane&15, row=(lane>>4)*4+reg  [m89/m91]
  const int obf = OUT_FLAG ? *flag : 1;
#pragma unroll
  for (int mi = 0; mi < 4; ++mi) {
#pragma unroll
    for (int ni = 0; ni < 4; ++ni) {
      const int row = bm + wm * 64 + mi * 16 + q * 4;
      const int col = bn + wn * 64 + ni * 16 + mr;
#pragma unroll
      for (int j = 0; j < 4; ++j) {
        const size_t off = (size_t)(row + j) * N + col;
        if (!OUT_FLAG || obf)
          ((unsigned short*)C)[off] = f2bf(acc[mi][ni][j]);
        else
          ((float*)C)[off] = acc[mi][ni][j];
      }
    }
  }
}

// ---------------------------------------------------------------------------
// Depthwise causal conv (width 4) + bias + SiLU.
// xzb: (ML,4096) bf16; x part = u16 cols [0,2048). Output xc (ML,2048) fp32.
// ---------------------------------------------------------------------------
__global__ __launch_bounds__(256) void conv_silu_kernel(
    const unsigned short* __restrict__ xzb, const void* __restrict__ cw,
    const void* __restrict__ cb, float* __restrict__ xc,
    const int* __restrict__ flag) {
  const int bf = *flag;
  const int idx = blockIdx.x * 256 + threadIdx.x;  // over ML*D_INNER
  const int d = idx & (D_INNER - 1);
  const int bl = idx >> 11;
  const int l = bl & (SEQ - 1);
  float w[4];
  if (bf) ld4<true>(cw, (size_t)d * 4, w);
  else ld4<false>(cw, (size_t)d * 4, w);
  const float bias = bf ? ld1<true>(cb, d) : ld1<false>(cb, d);
  const size_t base = (size_t)bl * 4096 + d;
  float acc = bias + w[3] * bf2f(xzb[base]);
  if (l >= 1) acc += w[2] * bf2f(xzb[base - 4096]);
  if (l >= 2) acc += w[1] * bf2f(xzb[base - 2 * 4096]);
  if (l >= 3) acc += w[0] * bf2f(xzb[base - 3 * 4096]);
  xc[idx] = acc / (1.f + __expf(-acc));  // silu
}

// ---------------------------------------------------------------------------
// dbl[m,e] = dot(xc[m,:], x_proj_w[e,:]), e < 96, K = 2048.
// ---------------------------------------------------------------------------
template <bool BF>
__device__ __forceinline__ void xproj_body(const float* __restrict__ xc,
                                           const void* __restrict__ W,
                                           float* __restrict__ dbl) {
  const int e = threadIdx.x;  // 0..95
  const int m = blockIdx.x * blockDim.y + threadIdx.y;
  const float* xr = xc + (size_t)m * D_INNER;
  const size_t woff = (size_t)e * D_INNER;
  float acc = 0.f;
#pragma unroll 4
  for (int k = 0; k < D_INNER; k += 4) {
    float a[4], b[4];
    ld4<false>(xr, k, a);
    ld4<BF>(W, woff + k, b);
    acc += a[0] * b[0] + a[1] * b[1] + a[2] * b[2] + a[3] * b[3];
  }
  dbl[(size_t)m * 96 + e] = acc;
}
__global__ void xproj_kernel(const float* __restrict__ xc,
                             const void* __restrict__ W,
                             float* __restrict__ dbl,
                             const int* __restrict__ flag) {
  if (*flag) xproj_body<true>(xc, W, dbl);
  else xproj_body<false>(xc, W, dbl);
}

// ---------------------------------------------------------------------------
// dt = softplus(dbl[:, :64] @ dt_proj_w^T + b) -> bf16 into xzb u16 cols
// [0,2048) (the x half is dead after conv).
// ---------------------------------------------------------------------------
template <bool BF>
__device__ __forceinline__ void dtproj_body(const float* __restrict__ dbl,
                                            const void* __restrict__ W,
                                            const void* __restrict__ bias,
                                            unsigned short* __restrict__ xzb) {
  const int idx = blockIdx.x * 256 + threadIdx.x;  // over ML*D_INNER
  const int d = idx & (D_INNER - 1);
  const int m = idx >> 11;
  const float* xr = dbl + (size_t)m * 96;  // dt_x = first 64 cols
  const size_t woff = (size_t)d * DT_RANK;
  float acc = ld1<BF>(bias, d);
#pragma unroll
  for (int k = 0; k < DT_RANK; k += 4) {
    float a[4], b[4];
    ld4<false>(xr, k, a);
    ld4<BF>(W, woff + k, b);
    acc += a[0] * b[0] + a[1] * b[1] + a[2] * b[2] + a[3] * b[3];
  }
  const float sp = (acc > 20.f) ? acc : log1pf(expf(acc));
  xzb[(size_t)m * 4096 + d] = f2bf(sp);
}
__global__ __launch_bounds__(256) void dtproj_kernel(
    const float* __restrict__ dbl, const void* __restrict__ W,
    const void* __restrict__ bias, unsigned short* __restrict__ xzb,
    const int* __restrict__ flag) {
  if (*flag) dtproj_body<true>(dbl, W, bias, xzb);
  else dtproj_body<false>(dbl, W, bias, xzb);
}

// ---------------------------------------------------------------------------
// Chunked selective scan, 3 passes. Group = (b, chunk c, d) -> 16 lanes (n).
// gid = blk*16+g ; d = gid&2047, c = (gid>>11)&7, b = gid>>14.
// Pass A: from h=0, compute chunk-final state S and dA-product P.
// ---------------------------------------------------------------------------
__global__ __launch_bounds__(256) void scan_passA(
    const unsigned short* __restrict__ xzb, const float* __restrict__ xc,
    const float* __restrict__ dbl, const void* __restrict__ A_log,
    const int* __restrict__ flag, float* __restrict__ S,
    float* __restrict__ P) {
  const int bf = *flag;
  const int tid = threadIdx.x;
  const int n = tid & 15;
  const int gid = blockIdx.x * 16 + (tid >> 4);
  const int d = gid & (D_INNER - 1);
  const int c = (gid >> 11) & (NCH - 1);
  const int b = gid >> 14;
  const float alog = bf ? ld1<true>(A_log, d * D_STATE + n)
                        : ld1<false>(A_log, d * D_STATE + n);
  const float a = -expf(alog);
  const size_t m0 = (size_t)b * SEQ + c * CL;
  float h = 0.f, p = 1.f;
#pragma unroll 4
  for (int t = 0; t < CL; ++t) {
    const size_t m = m0 + t;
    const float dtv = bf2f(xzb[m * 4096 + d]);
    const float xv = xc[m * 2048 + d];
    const float Bv = dbl[m * 96 + DT_RANK + n];
    const float dA = __expf(dtv * a);
    h = dA * h + dtv * Bv * xv;
    p *= dA;
  }
  const size_t sidx = ((((size_t)b * NCH + c) * D_INNER) + d) * 16 + n;
  S[sidx] = h;
  P[sidx] = p;
}

// Pass B: serial prefix over the 8 chunks; S[c] becomes the INITIAL state of
// chunk c. One thread per (b,d,n) = 131072.
__global__ __launch_bounds__(256) void scan_passB(float* __restrict__ S,
                                                  const float* __restrict__ P) {
  const int idx = blockIdx.x * 256 + threadIdx.x;
  const int n = idx & 15;
  const int d = (idx >> 4) & (D_INNER - 1);
  const int b = idx >> 15;
  float h = 0.f;
#pragma unroll
  for (int c = 0; c < NCH; ++c) {
    const size_t sidx = ((((size_t)b * NCH + c) * D_INNER) + d) * 16 + n;
    const float s = S[sidx], p = P[sidx];
    S[sidx] = h;  // init for chunk c
    h = p * h + s;
  }
}

// Pass C: replay chunk from true init state; emit y = (sum_n h*C + D*x)*silu(z)
// as bf16 into ybf.
__global__ __launch_bounds__(256) void scan_passC(
    const unsigned short* __restrict__ xzb, const float* __restrict__ xc,
    const float* __restrict__ dbl, const void* __restrict__ A_log,
    const void* __restrict__ Dp, const float* __restrict__ S,
    const int* __restrict__ flag, unsigned short* __restrict__ ybf) {
  const int bf = *flag;
  const int tid = threadIdx.x;
  const int n = tid & 15;
  const int gid = blockIdx.x * 16 + (tid >> 4);
  const int d = gid & (D_INNER - 1);
  const int c = (gid >> 11) & (NCH - 1);
  const int b = gid >> 14;
  const float alog = bf ? ld1<true>(A_log, d * D_STATE + n)
                        : ld1<false>(A_log, d * D_STATE + n);
  const float a = -expf(alog);
  const float Dv = bf ? ld1<true>(Dp, d) : ld1<false>(Dp, d);
  const size_t m0 = (size_t)b * SEQ + c * CL;
  float h = S[((((size_t)b * NCH + c) * D_INNER) + d) * 16 + n];
#pragma unroll 4
  for (int t = 0; t < CL; ++t) {
    const size_t m = m0 + t;
    const float dtv = bf2f(xzb[m * 4096 + d]);
    const float xv = xc[m * 2048 + d];
    const float Bv = dbl[m * 96 + DT_RANK + n];
    const float Cv = dbl[m * 96 + DT_RANK + D_STATE + n];
    const float dA = __expf(dtv * a);
    h = dA * h + dtv * Bv * xv;
    float p = h * Cv;
    p += __shfl_xor(p, 1);
    p += __shfl_xor(p, 2);
    p += __shfl_xor(p, 4);
    p += __shfl_xor(p, 8);
    if (n == 0) {
      const float zv = bf2f(xzb[m * 4096 + 2048 + d]);
      const float yv = p + Dv * xv;
      ybf[m * 2048 + d] = f2bf(yv * (zv / (1.f + __expf(-zv))));
    }
  }
}

// ---------------------------------------------------------------------------
extern "C" void kernel_launch(void* const* d_in, const int* in_sizes, int n_in,
                              void* d_out, int out_size, void* d_ws,
                              size_t ws_size, hipStream_t stream) {
  const void* x = d_in[0];
  const void* in_proj_w = d_in[1];
  const void* conv_w = d_in[2];
  const void* conv_b = d_in[3];
  const void* x_proj_w = d_in[4];
  const void* dt_proj_w = d_in[5];
  const void* dt_proj_b = d_in[6];
  const void* A_log = d_in[7];
  const void* D_param = d_in[8];
  const void* out_proj_w = d_in[9];

  // ws layout (bytes), ~171 MB total:
  //  [0,256): flag | xzb 64MB bf16 (ML x 4096; x-half becomes dt after conv)
  //  xc 64MB fp32 (pre-conv: holds x_bf 16MB + ipw_bf 8MB; post-scan: opw_bf)
  //  dbl 3MB fp32 | ybf 32MB bf16 | S 4MB | P 4MB
  char* wsb = (char*)d_ws;
  int* flag = (int*)wsb;
  unsigned short* xzb = (unsigned short*)(wsb + 256);
  float* xc = (float*)(wsb + 256 + (size_t)ML * 4096 * 2);
  float* dbl = (float*)((char*)xc + (size_t)ML * 2048 * 4);
  unsigned short* ybf = (unsigned short*)((char*)dbl + (size_t)ML * 96 * 4);
  float* S = (float*)((char*)ybf + (size_t)ML * 2048 * 2);
  float* P = (float*)((char*)S + (size_t)BATCH * NCH * D_INNER * 16 * 4);
  unsigned short* x_bf = (unsigned short*)xc;        // lives until K1 done
  unsigned short* ipw_bf = x_bf + (size_t)ML * 1024; // lives until K1 done
  unsigned short* opw_bf = (unsigned short*)xc;      // written after pass C

  // K0: detect input dtype (fp32 vs bf16)
  detect_kernel<<<1, 256, 0, stream>>>((const unsigned int*)x, flag);
  // convert x and in_proj_w to bf16
  cvt_kernel<<<(ML * 1024) / 1024, 256, 0, stream>>>(x, x_bf, ML * 1024, flag);
  cvt_kernel<<<(4096 * 1024) / 1024, 256, 0, stream>>>(in_proj_w, ipw_bf,
                                                       4096 * 1024, flag);
  // K1: xz = x @ in_proj_w^T (M=8192,N=4096,K=1024), bf16 out
  {
    dim3 g(4096 / 128, ML / 128);
    gemm_mfma<false><<<g, 256, 0, stream>>>(x_bf, ipw_bf, xzb, ML, 4096, 1024,
                                            flag);
  }
  // K2: causal depthwise conv + SiLU -> xc fp32 (overwrites x_bf/ipw_bf: dead)
  conv_silu_kernel<<<(ML * D_INNER) / 256, 256, 0, stream>>>(xzb, conv_w,
                                                             conv_b, xc, flag);
  // K3: dbl = xc @ x_proj_w^T (N=96, K=2048)
  {
    dim3 blk(96, 4);
    xproj_kernel<<<ML / 4, blk, 0, stream>>>(xc, x_proj_w, dbl, flag);
  }
  // K4: dt = softplus(...) -> bf16 into xzb x-half
  dtproj_kernel<<<(ML * D_INNER) / 256, 256, 0, stream>>>(dbl, dt_proj_w,
                                                          dt_proj_b, xzb, flag);
  // K5: chunked scan (A: chunk states, B: prefix, C: replay + y epilogue)
  scan_passA<<<(BATCH * NCH * D_INNER) / 16, 256, 0, stream>>>(
      xzb, xc, dbl, A_log, flag, S, P);
  scan_passB<<<(BATCH * D_INNER * 16) / 256, 256, 0, stream>>>(S, P);
  scan_passC<<<(BATCH * NCH * D_INNER) / 16, 256, 0, stream>>>(
      xzb, xc, dbl, A_log, D_param, S, flag, ybf);
  // convert out_proj_w (xc region now dead)
  cvt_kernel<<<(1024 * 2048) / 1024, 256, 0, stream>>>(out_proj_w, opw_bf,
                                                       1024 * 2048, flag);
  // K6: out = y @ out_proj_w^T (M=8192,N=1024,K=2048), out dtype per flag
  {
    dim3 g(1024 / 128, ML / 128);
    gemm_mfma<true><<<g, 256, 0, stream>>>(ybf, opw_bf, d_out, ML, 1024, 2048,
                                           flag);
  }
}

// Round 5
// 975.475 us; speedup vs baseline: 4.8745x; 2.4558x over previous
//
#include <hip/hip_runtime.h>
#include <math.h>

#define D_MODEL 1024
#define D_STATE 16
#define D_CONV 4
#define D_INNER 2048
#define DT_RANK 64
#define BATCH 4
#define SEQ 2048
#define ML (BATCH * SEQ)  // 8192 rows
#define NCH 8             // scan chunks per sequence
#define CL (SEQ / NCH)    // 256 steps per chunk

typedef __attribute__((ext_vector_type(8))) short short8;
typedef __attribute__((ext_vector_type(4))) float f32x4;

// ---------------------------------------------------------------------------
// dtype helpers: inputs may be fp32 (expected) or bf16 (runtime-detected).
// ---------------------------------------------------------------------------
__device__ __forceinline__ float bf2f(unsigned short u) {
  union { unsigned int i; float f; } v;
  v.i = ((unsigned int)u) << 16;
  return v.f;
}
__device__ __forceinline__ unsigned short f2bf(float f) {
  union { float f; unsigned int i; } u;
  u.f = f;
  unsigned int r = u.i + 0x7fffu + ((u.i >> 16) & 1u);  // RNE
  return (unsigned short)(r >> 16);
}
template <bool BF>
__device__ __forceinline__ float ld1(const void* p, size_t i) {
  if constexpr (BF) return bf2f(((const unsigned short*)p)[i]);
  else return ((const float*)p)[i];
}
template <bool BF>
__device__ __forceinline__ void ld4(const void* p, size_t i, float o[4]) {
  if constexpr (BF) {
    ushort4 v = *(const ushort4*)((const unsigned short*)p + i);
    o[0] = bf2f(v.x); o[1] = bf2f(v.y); o[2] = bf2f(v.z); o[3] = bf2f(v.w);
  } else {
    float4 v = *(const float4*)((const float*)p + i);
    o[0] = v.x; o[1] = v.y; o[2] = v.z; o[3] = v.w;
  }
}

// async global->LDS, 16 B per lane; lds base must be wave-uniform.
__device__ __forceinline__ void gl_lds16(const unsigned short* g,
                                         unsigned short* l) {
  __builtin_amdgcn_global_load_lds(
      (const __attribute__((address_space(1))) void*)g,
      (__attribute__((address_space(3))) void*)l, 16, 0, 0);
}

// ---------------------------------------------------------------------------
// Runtime dtype detection (see R2 notes): flag=1 means bf16 inputs.
// ---------------------------------------------------------------------------
__global__ void detect_kernel(const unsigned int* __restrict__ xw, int* flag) {
  __shared__ int cnt;
  if (threadIdx.x == 0) cnt = 0;
  __syncthreads();
  unsigned int w = xw[threadIdx.x];
  unsigned int e = (w >> 7) & 0xffu;
  if (e < 100u || e > 145u) atomicAdd(&cnt, 1);
  __syncthreads();
  if (threadIdx.x == 0) flag[0] = (cnt < 32) ? 1 : 0;
}

// ---------------------------------------------------------------------------
// fp32->bf16 conversion (or copy when already bf16). n multiple of 1024.
// ---------------------------------------------------------------------------
__global__ __launch_bounds__(256) void cvt_kernel(
    const void* __restrict__ in, unsigned short* __restrict__ out, int n,
    const int* __restrict__ flag) {
  const int i = (blockIdx.x * 256 + threadIdx.x) * 4;
  if (i >= n) return;
  if (*flag) {
    *(ushort4*)(out + i) = *(const ushort4*)((const unsigned short*)in + i);
  } else {
    float4 v = *(const float4*)((const float*)in + i);
    ushort4 o;
    o.x = f2bf(v.x); o.y = f2bf(v.y); o.z = f2bf(v.z); o.w = f2bf(v.w);
    *(ushort4*)(out + i) = o;
  }
}

// x_proj_w (96 x 2048) -> bf16 padded to 128 rows (rows 96..127 = 0).
__global__ __launch_bounds__(256) void cvtpad_kernel(
    const void* __restrict__ in, unsigned short* __restrict__ out,
    const int* __restrict__ flag) {
  const int i = (blockIdx.x * 256 + threadIdx.x) * 4;  // over 128*2048
  const int row = i >> 11;
  ushort4 o;
  if (row < 96) {
    if (*flag) {
      o = *(const ushort4*)((const unsigned short*)in + i);
    } else {
      float4 v = *(const float4*)((const float*)in + i);
      o.x = f2bf(v.x); o.y = f2bf(v.y); o.z = f2bf(v.z); o.w = f2bf(v.w);
    }
  } else {
    o.x = o.y = o.z = o.w = 0;
  }
  *(ushort4*)(out + i) = o;
}

// ---------------------------------------------------------------------------
// MFMA bf16 GEMM: C[M,N] = A * B^T (+epilogue). A (.,lda) bf16, B (.,ldb)
// bf16, row-major. 128x128 tile, BK=32, 256 thr = 4 waves (2x2), 64x64/wave,
// 16x16x32 MFMA, global_load_lds width-16 staging (m97 structure).
// EPI 0: store bf16. EPI 1: store per *flag (bf16/fp32). EPI 2: softplus
// (acc + bias[col]) then bf16 store.
// ---------------------------------------------------------------------------
template <int EPI>
__global__ __launch_bounds__(256) void gemm_mfma(
    const unsigned short* __restrict__ A, int lda,
    const unsigned short* __restrict__ B, int ldb, void* __restrict__ C,
    int ldc, int K, const void* __restrict__ bias,
    const int* __restrict__ flag) {
  __shared__ unsigned short As[128 * 32];
  __shared__ unsigned short Bs[128 * 32];
  const int tid = threadIdx.x;
  const int l = tid & 63, w = tid >> 6;
  const int bm = blockIdx.y * 128;
  const int bn = blockIdx.x * 128;
  // staging: lane l of wave w loads 16B = row (w*16 + l/4), col chunk (l%4)*8
  const int r0 = w * 16 + (l >> 2);
  const int cc = (l & 3) * 8;
  const unsigned short* Ap0 = A + (size_t)(bm + r0) * lda + cc;
  const unsigned short* Ap1 = A + (size_t)(bm + r0 + 64) * lda + cc;
  const unsigned short* Bp0 = B + (size_t)(bn + r0) * ldb + cc;
  const unsigned short* Bp1 = B + (size_t)(bn + r0 + 64) * ldb + cc;
  // fragment coords
  const int q = l >> 4, mr = l & 15;
  const int wm = w >> 1, wn = w & 1;
  f32x4 acc[4][4] = {};
  for (int k0 = 0; k0 < K; k0 += 32) {
    gl_lds16(Ap0 + k0, As + w * 512);
    gl_lds16(Ap1 + k0, As + 2048 + w * 512);
    gl_lds16(Bp0 + k0, Bs + w * 512);
    gl_lds16(Bp1 + k0, Bs + 2048 + w * 512);
    __syncthreads();  // drains vmcnt (global_load_lds)
    short8 af[4], bfr[4];
#pragma unroll
    for (int mi = 0; mi < 4; ++mi)
      af[mi] = *(const short8*)&As[(wm * 64 + mi * 16 + mr) * 32 + q * 8];
#pragma unroll
    for (int ni = 0; ni < 4; ++ni)
      bfr[ni] = *(const short8*)&Bs[(wn * 64 + ni * 16 + mr) * 32 + q * 8];
#pragma unroll
    for (int mi = 0; mi < 4; ++mi)
#pragma unroll
      for (int ni = 0; ni < 4; ++ni)
        acc[mi][ni] = __builtin_amdgcn_mfma_f32_16x16x32_bf16(
            af[mi], bfr[ni], acc[mi][ni], 0, 0, 0);
    __syncthreads();
  }
  // epilogue: C/D layout col=lane&15, row=(lane>>4)*4+reg  [m89/m91]
  const int bf = *flag;
#pragma unroll
  for (int mi = 0; mi < 4; ++mi) {
#pragma unroll
    for (int ni = 0; ni < 4; ++ni) {
      const int row = bm + wm * 64 + mi * 16 + q * 4;
      const int col = bn + wn * 64 + ni * 16 + mr;
#pragma unroll
      for (int j = 0; j < 4; ++j) {
        float v = acc[mi][ni][j];
        const size_t off = (size_t)(row + j) * ldc + col;
        if (EPI == 2) {
          v += bf ? ld1<true>(bias, col) : ld1<false>(bias, col);
          v = (v > 20.f) ? v : log1pf(expf(v));
          ((unsigned short*)C)[off] = f2bf(v);
        } else if (EPI == 1) {
          if (bf) ((unsigned short*)C)[off] = f2bf(v);
          else ((float*)C)[off] = v;
        } else {
          ((unsigned short*)C)[off] = f2bf(v);
        }
      }
    }
  }
}

// ---------------------------------------------------------------------------
// Depthwise causal conv (width 4) + bias + SiLU.
// xzb: (ML,4096) bf16; x part = cols [0,2048). Output xcb (ML,2048) bf16.
// ---------------------------------------------------------------------------
__global__ __launch_bounds__(256) void conv_silu_kernel(
    const unsigned short* __restrict__ xzb, const void* __restrict__ cw,
    const void* __restrict__ cb, unsigned short* __restrict__ xcb,
    const int* __restrict__ flag) {
  const int bf = *flag;
  const int idx = blockIdx.x * 256 + threadIdx.x;  // over ML*D_INNER
  const int d = idx & (D_INNER - 1);
  const int bl = idx >> 11;
  const int l = bl & (SEQ - 1);
  float w[4];
  if (bf) ld4<true>(cw, (size_t)d * 4, w);
  else ld4<false>(cw, (size_t)d * 4, w);
  const float bias = bf ? ld1<true>(cb, d) : ld1<false>(cb, d);
  const size_t base = (size_t)bl * 4096 + d;
  float acc = bias + w[3] * bf2f(xzb[base]);
  if (l >= 1) acc += w[2] * bf2f(xzb[base - 4096]);
  if (l >= 2) acc += w[1] * bf2f(xzb[base - 2 * 4096]);
  if (l >= 3) acc += w[0] * bf2f(xzb[base - 3 * 4096]);
  xcb[idx] = f2bf(acc / (1.f + __expf(-acc)));  // silu
}

// ---------------------------------------------------------------------------
// Chunked selective scan, 3 passes. Group = (b, chunk c, d) -> 16 lanes (n).
// Pass A: from h=0, compute chunk-final state S and dA-product P.
// ---------------------------------------------------------------------------
__global__ __launch_bounds__(256) void scan_passA(
    const unsigned short* __restrict__ xzb,
    const unsigned short* __restrict__ xcb,
    const unsigned short* __restrict__ dbl, const void* __restrict__ A_log,
    const int* __restrict__ flag, float* __restrict__ S,
    float* __restrict__ P) {
  const int bf = *flag;
  const int tid = threadIdx.x;
  const int n = tid & 15;
  const int gid = blockIdx.x * 16 + (tid >> 4);
  const int d = gid & (D_INNER - 1);
  const int c = (gid >> 11) & (NCH - 1);
  const int b = gid >> 14;
  const float alog = bf ? ld1<true>(A_log, d * D_STATE + n)
                        : ld1<false>(A_log, d * D_STATE + n);
  const float a = -expf(alog);
  const size_t m0 = (size_t)b * SEQ + c * CL;
  float h = 0.f, p = 1.f;
#pragma unroll 4
  for (int t = 0; t < CL; ++t) {
    const size_t m = m0 + t;
    const float dtv = bf2f(xzb[m * 4096 + d]);
    const float xv = bf2f(xcb[m * 2048 + d]);
    const float Bv = bf2f(dbl[m * 128 + DT_RANK + n]);
    const float dA = __expf(dtv * a);
    h = dA * h + dtv * Bv * xv;
    p *= dA;
  }
  const size_t sidx = ((((size_t)b * NCH + c) * D_INNER) + d) * 16 + n;
  S[sidx] = h;
  P[sidx] = p;
}

// Pass B: serial prefix over the 8 chunks; S[c] becomes the INITIAL state of
// chunk c. One thread per (b,d,n) = 131072.
__global__ __launch_bounds__(256) void scan_passB(float* __restrict__ S,
                                                  const float* __restrict__ P) {
  const int idx = blockIdx.x * 256 + threadIdx.x;
  const int n = idx & 15;
  const int d = (idx >> 4) & (D_INNER - 1);
  const int b = idx >> 15;
  float h = 0.f;
#pragma unroll
  for (int c = 0; c < NCH; ++c) {
    const size_t sidx = ((((size_t)b * NCH + c) * D_INNER) + d) * 16 + n;
    const float s = S[sidx], p = P[sidx];
    S[sidx] = h;  // init for chunk c
    h = p * h + s;
  }
}

// Pass C: replay chunk from true init state; y = (sum_n h*C + D*x)*silu(z).
__global__ __launch_bounds__(256) void scan_passC(
    const unsigned short* __restrict__ xzb,
    const unsigned short* __restrict__ xcb,
    const unsigned short* __restrict__ dbl, const void* __restrict__ A_log,
    const void* __restrict__ Dp, const float* __restrict__ S,
    const int* __restrict__ flag, unsigned short* __restrict__ ybf) {
  const int bf = *flag;
  const int tid = threadIdx.x;
  const int n = tid & 15;
  const int gid = blockIdx.x * 16 + (tid >> 4);
  const int d = gid & (D_INNER - 1);
  const int c = (gid >> 11) & (NCH - 1);
  const int b = gid >> 14;
  const float alog = bf ? ld1<true>(A_log, d * D_STATE + n)
                        : ld1<false>(A_log, d * D_STATE + n);
  const float a = -expf(alog);
  const float Dv = bf ? ld1<true>(Dp, d) : ld1<false>(Dp, d);
  const size_t m0 = (size_t)b * SEQ + c * CL;
  float h = S[((((size_t)b * NCH + c) * D_INNER) + d) * 16 + n];
#pragma unroll 4
  for (int t = 0; t < CL; ++t) {
    const size_t m = m0 + t;
    const float dtv = bf2f(xzb[m * 4096 + d]);
    const float xv = bf2f(xcb[m * 2048 + d]);
    const float Bv = bf2f(dbl[m * 128 + DT_RANK + n]);
    const float Cv = bf2f(dbl[m * 128 + DT_RANK + D_STATE + n]);
    const float dA = __expf(dtv * a);
    h = dA * h + dtv * Bv * xv;
    float p = h * Cv;
    p += __shfl_xor(p, 1);
    p += __shfl_xor(p, 2);
    p += __shfl_xor(p, 4);
    p += __shfl_xor(p, 8);
    if (n == 0) {
      const float zv = bf2f(xzb[m * 4096 + 2048 + d]);
      const float yv = p + Dv * xv;
      ybf[m * 2048 + d] = f2bf(yv * (zv / (1.f + __expf(-zv))));
    }
  }
}

// ---------------------------------------------------------------------------
extern "C" void kernel_launch(void* const* d_in, const int* in_sizes, int n_in,
                              void* d_out, int out_size, void* d_ws,
                              size_t ws_size, hipStream_t stream) {
  const void* x = d_in[0];
  const void* in_proj_w = d_in[1];
  const void* conv_w = d_in[2];
  const void* conv_b = d_in[3];
  const void* x_proj_w = d_in[4];
  const void* dt_proj_w = d_in[5];
  const void* dt_proj_b = d_in[6];
  const void* A_log = d_in[7];
  const void* D_param = d_in[8];
  const void* out_proj_w = d_in[9];

  // ws layout (~143 MB):
  // flag 256B | xzb 64MB (ML x 4096 bf16; x-half becomes dt after conv) |
  // xcb 32MB (conv out bf16; pre-conv hosts x_bf 16MB + ipw_bf 8MB) |
  // dbl 2MB (ML x 128 bf16) | ybf 32MB | S 4MB | P 4MB | opw 4MB |
  // xpw_pad 512KB | dtw 256KB
  char* wsb = (char*)d_ws;
  int* flag = (int*)wsb;
  unsigned short* xzb = (unsigned short*)(wsb + 256);
  unsigned short* xcb = xzb + (size_t)ML * 4096;
  unsigned short* dbl = xcb + (size_t)ML * 2048;
  unsigned short* ybf = dbl + (size_t)ML * 128;
  float* S = (float*)(ybf + (size_t)ML * 2048);
  float* P = S + (size_t)BATCH * NCH * D_INNER * 16;
  unsigned short* opw_bf = (unsigned short*)(P + (size_t)BATCH * NCH * D_INNER * 16);
  unsigned short* xpw_pad = opw_bf + (size_t)1024 * 2048;
  unsigned short* dtw_bf = xpw_pad + (size_t)128 * 2048;
  unsigned short* x_bf = xcb;                         // dead after K1
  unsigned short* ipw_bf = xcb + (size_t)ML * 1024;   // dead after K1

  // K0: detect input dtype (fp32 vs bf16)
  detect_kernel<<<1, 256, 0, stream>>>((const unsigned int*)x, flag);
  // conversions
  cvt_kernel<<<(ML * 1024) / 1024, 256, 0, stream>>>(x, x_bf, ML * 1024, flag);
  cvt_kernel<<<(4096 * 1024) / 1024, 256, 0, stream>>>(in_proj_w, ipw_bf,
                                                       4096 * 1024, flag);
  // K1: xz = x @ in_proj_w^T (M=8192,N=4096,K=1024) -> xzb bf16
  {
    dim3 g(4096 / 128, ML / 128);
    gemm_mfma<0><<<g, 256, 0, stream>>>(x_bf, 1024, ipw_bf, 1024, xzb, 4096,
                                        1024, nullptr, flag);
  }
  // K2: causal depthwise conv + SiLU -> xcb bf16 (x_bf/ipw_bf now dead)
  conv_silu_kernel<<<(ML * D_INNER) / 256, 256, 0, stream>>>(xzb, conv_w,
                                                             conv_b, xcb, flag);
  // weight conversions for the small GEMMs
  cvtpad_kernel<<<(128 * 2048) / 1024, 256, 0, stream>>>(x_proj_w, xpw_pad,
                                                         flag);
  cvt_kernel<<<(2048 * 64) / 1024, 256, 0, stream>>>(dt_proj_w, dtw_bf,
                                                     2048 * 64, flag);
  // K3: dbl = xc @ x_proj_w^T (M=8192, N=128(pad), K=2048) -> bf16, ldc=128
  {
    dim3 g(1, ML / 128);
    gemm_mfma<0><<<g, 256, 0, stream>>>(xcb, 2048, xpw_pad, 2048, dbl, 128,
                                        2048, nullptr, flag);
  }
  // K4: dt = softplus(dbl[:,:64] @ dt_proj_w^T + b) -> xzb x-half (ldc=4096)
  {
    dim3 g(2048 / 128, ML / 128);
    gemm_mfma<2><<<g, 256, 0, stream>>>(dbl, 128, dtw_bf, 64, xzb, 4096, 64,
                                        dt_proj_b, flag);
  }
  // K5: chunked scan (A: chunk states, B: prefix, C: replay + y epilogue)
  scan_passA<<<(BATCH * NCH * D_INNER) / 16, 256, 0, stream>>>(
      xzb, xcb, dbl, A_log, flag, S, P);
  scan_passB<<<(BATCH * D_INNER * 16) / 256, 256, 0, stream>>>(S, P);
  scan_passC<<<(BATCH * NCH * D_INNER) / 16, 256, 0, stream>>>(
      xzb, xcb, dbl, A_log, D_param, S, flag, ybf);
  // K6: out = y @ out_proj_w^T (M=8192,N=1024,K=2048), out dtype per flag
  cvt_kernel<<<(1024 * 2048) / 1024, 256, 0, stream>>>(out_proj_w, opw_bf,
                                                       1024 * 2048, flag);
  {
    dim3 g(1024 / 128, ML / 128);
    gemm_mfma<1><<<g, 256, 0, stream>>>(ybf, 2048, opw_bf, 2048, d_out, 1024,
                                        2048, nullptr, flag);
  }
}

// Round 6
// 608.790 us; speedup vs baseline: 7.8104x; 1.6023x over previous
//
#include <hip/hip_runtime.h>
#include <math.h>

#define D_MODEL 1024
#define D_STATE 16
#define D_CONV 4
#define D_INNER 2048
#define DT_RANK 64
#define BATCH 4
#define SEQ 2048
#define ML (BATCH * SEQ)  // 8192 rows
#define NCH 32            // scan chunks per sequence
#define CL (SEQ / NCH)    // 64 steps per chunk

typedef __attribute__((ext_vector_type(8))) short short8;
typedef __attribute__((ext_vector_type(8))) unsigned short u16x8;
typedef __attribute__((ext_vector_type(4))) float f32x4;

// ---------------------------------------------------------------------------
// dtype helpers: inputs may be fp32 (expected) or bf16 (runtime-detected).
// ---------------------------------------------------------------------------
__device__ __forceinline__ float bf2f(unsigned short u) {
  union { unsigned int i; float f; } v;
  v.i = ((unsigned int)u) << 16;
  return v.f;
}
__device__ __forceinline__ unsigned short f2bf(float f) {
  union { float f; unsigned int i; } u;
  u.f = f;
  unsigned int r = u.i + 0x7fffu + ((u.i >> 16) & 1u);  // RNE
  return (unsigned short)(r >> 16);
}
template <bool BF>
__device__ __forceinline__ float ld1(const void* p, size_t i) {
  if constexpr (BF) return bf2f(((const unsigned short*)p)[i]);
  else return ((const float*)p)[i];
}
template <bool BF>
__device__ __forceinline__ void ld4(const void* p, size_t i, float o[4]) {
  if constexpr (BF) {
    ushort4 v = *(const ushort4*)((const unsigned short*)p + i);
    o[0] = bf2f(v.x); o[1] = bf2f(v.y); o[2] = bf2f(v.z); o[3] = bf2f(v.w);
  } else {
    float4 v = *(const float4*)((const float*)p + i);
    o[0] = v.x; o[1] = v.y; o[2] = v.z; o[3] = v.w;
  }
}

// async global->LDS, 16 B per lane; lds base must be wave-uniform.
__device__ __forceinline__ void gl_lds16(const unsigned short* g,
                                         unsigned short* l) {
  __builtin_amdgcn_global_load_lds(
      (const __attribute__((address_space(1))) void*)g,
      (__attribute__((address_space(3))) void*)l, 16, 0, 0);
}

// ---------------------------------------------------------------------------
// Runtime dtype detection (see R2 notes): flag=1 means bf16 inputs.
// ---------------------------------------------------------------------------
__global__ void detect_kernel(const unsigned int* __restrict__ xw, int* flag) {
  __shared__ int cnt;
  if (threadIdx.x == 0) cnt = 0;
  __syncthreads();
  unsigned int w = xw[threadIdx.x];
  unsigned int e = (w >> 7) & 0xffu;
  if (e < 100u || e > 145u) atomicAdd(&cnt, 1);
  __syncthreads();
  if (threadIdx.x == 0) flag[0] = (cnt < 32) ? 1 : 0;
}

// ---------------------------------------------------------------------------
// fp32->bf16 conversion (or copy when already bf16). n multiple of 1024.
// ---------------------------------------------------------------------------
__global__ __launch_bounds__(256) void cvt_kernel(
    const void* __restrict__ in, unsigned short* __restrict__ out, int n,
    const int* __restrict__ flag) {
  const int i = (blockIdx.x * 256 + threadIdx.x) * 4;
  if (i >= n) return;
  if (*flag) {
    *(ushort4*)(out + i) = *(const ushort4*)((const unsigned short*)in + i);
  } else {
    float4 v = *(const float4*)((const float*)in + i);
    ushort4 o;
    o.x = f2bf(v.x); o.y = f2bf(v.y); o.z = f2bf(v.z); o.w = f2bf(v.w);
    *(ushort4*)(out + i) = o;
  }
}

// x_proj_w (96 x 2048) -> bf16 padded to 128 rows (rows 96..127 = 0).
__global__ __launch_bounds__(256) void cvtpad_kernel(
    const void* __restrict__ in, unsigned short* __restrict__ out,
    const int* __restrict__ flag) {
  const int i = (blockIdx.x * 256 + threadIdx.x) * 4;  // over 128*2048
  const int row = i >> 11;
  ushort4 o;
  if (row < 96) {
    if (*flag) {
      o = *(const ushort4*)((const unsigned short*)in + i);
    } else {
      float4 v = *(const float4*)((const float*)in + i);
      o.x = f2bf(v.x); o.y = f2bf(v.y); o.z = f2bf(v.z); o.w = f2bf(v.w);
    }
  } else {
    o.x = o.y = o.z = o.w = 0;
  }
  *(ushort4*)(out + i) = o;
}

// ---------------------------------------------------------------------------
// MFMA bf16 GEMM: C[M,N] = A * B^T (+epilogue). A (.,lda) bf16, B (.,ldb)
// bf16, row-major. 128x128 tile, BK=32, 256 thr = 4 waves (2x2), 64x64/wave,
// 16x16x32 MFMA, global_load_lds width-16 staging (m97 structure).
// EPI 0: store bf16. EPI 1: store per *flag (bf16/fp32). EPI 2: softplus
// (acc + bias[col]) then bf16 store.
// ---------------------------------------------------------------------------
template <int EPI>
__global__ __launch_bounds__(256) void gemm_mfma(
    const unsigned short* __restrict__ A, int lda,
    const unsigned short* __restrict__ B, int ldb, void* __restrict__ C,
    int ldc, int K, const void* __restrict__ bias,
    const int* __restrict__ flag) {
  __shared__ unsigned short As[128 * 32];
  __shared__ unsigned short Bs[128 * 32];
  const int tid = threadIdx.x;
  const int l = tid & 63, w = tid >> 6;
  const int bm = blockIdx.y * 128;
  const int bn = blockIdx.x * 128;
  // staging: lane l of wave w loads 16B = row (w*16 + l/4), col chunk (l%4)*8
  const int r0 = w * 16 + (l >> 2);
  const int cc = (l & 3) * 8;
  const unsigned short* Ap0 = A + (size_t)(bm + r0) * lda + cc;
  const unsigned short* Ap1 = A + (size_t)(bm + r0 + 64) * lda + cc;
  const unsigned short* Bp0 = B + (size_t)(bn + r0) * ldb + cc;
  const unsigned short* Bp1 = B + (size_t)(bn + r0 + 64) * ldb + cc;
  // fragment coords
  const int q = l >> 4, mr = l & 15;
  const int wm = w >> 1, wn = w & 1;
  f32x4 acc[4][4] = {};
  for (int k0 = 0; k0 < K; k0 += 32) {
    gl_lds16(Ap0 + k0, As + w * 512);
    gl_lds16(Ap1 + k0, As + 2048 + w * 512);
    gl_lds16(Bp0 + k0, Bs + w * 512);
    gl_lds16(Bp1 + k0, Bs + 2048 + w * 512);
    __syncthreads();  // drains vmcnt (global_load_lds)
    short8 af[4], bfr[4];
#pragma unroll
    for (int mi = 0; mi < 4; ++mi)
      af[mi] = *(const short8*)&As[(wm * 64 + mi * 16 + mr) * 32 + q * 8];
#pragma unroll
    for (int ni = 0; ni < 4; ++ni)
      bfr[ni] = *(const short8*)&Bs[(wn * 64 + ni * 16 + mr) * 32 + q * 8];
#pragma unroll
    for (int mi = 0; mi < 4; ++mi)
#pragma unroll
      for (int ni = 0; ni < 4; ++ni)
        acc[mi][ni] = __builtin_amdgcn_mfma_f32_16x16x32_bf16(
            af[mi], bfr[ni], acc[mi][ni], 0, 0, 0);
    __syncthreads();
  }
  // epilogue: C/D layout col=lane&15, row=(lane>>4)*4+reg  [m89/m91]
  const int bf = *flag;
#pragma unroll
  for (int mi = 0; mi < 4; ++mi) {
#pragma unroll
    for (int ni = 0; ni < 4; ++ni) {
      const int row = bm + wm * 64 + mi * 16 + q * 4;
      const int col = bn + wn * 64 + ni * 16 + mr;
#pragma unroll
      for (int j = 0; j < 4; ++j) {
        float v = acc[mi][ni][j];
        const size_t off = (size_t)(row + j) * ldc + col;
        if (EPI == 2) {
          v += bf ? ld1<true>(bias, col) : ld1<false>(bias, col);
          v = (v > 20.f) ? v : log1pf(expf(v));
          ((unsigned short*)C)[off] = f2bf(v);
        } else if (EPI == 1) {
          if (bf) ((unsigned short*)C)[off] = f2bf(v);
          else ((float*)C)[off] = v;
        } else {
          ((unsigned short*)C)[off] = f2bf(v);
        }
      }
    }
  }
}

// ---------------------------------------------------------------------------
// Depthwise causal conv (width 4) + bias + SiLU, 4 channels per thread.
// xzb: (ML,4096) bf16; x part = cols [0,2048). Output xcb (ML,2048) bf16.
// ---------------------------------------------------------------------------
__global__ __launch_bounds__(256) void conv_silu_kernel(
    const unsigned short* __restrict__ xzb, const void* __restrict__ cw,
    const void* __restrict__ cb, unsigned short* __restrict__ xcb,
    const int* __restrict__ flag) {
  const int bf = *flag;
  const int e = (blockIdx.x * 256 + threadIdx.x) * 4;  // over ML*D_INNER
  const int d = e & (D_INNER - 1);
  const int bl = e >> 11;
  const int l = bl & (SEQ - 1);
  const size_t base = (size_t)bl * 4096 + d;
  float x0[4], x1[4] = {}, x2[4] = {}, x3[4] = {};
  ld4<true>(xzb, base, x0);
  if (l >= 1) ld4<true>(xzb, base - 4096, x1);
  if (l >= 2) ld4<true>(xzb, base - 2 * 4096, x2);
  if (l >= 3) ld4<true>(xzb, base - 3 * 4096, x3);
  ushort4 o;
  unsigned short* op = (unsigned short*)&o;
#pragma unroll
  for (int i = 0; i < 4; ++i) {
    float w[4];
    if (bf) ld4<true>(cw, (size_t)(d + i) * 4, w);
    else ld4<false>(cw, (size_t)(d + i) * 4, w);
    const float bias = bf ? ld1<true>(cb, d + i) : ld1<false>(cb, d + i);
    float acc = bias + w[3] * x0[i] + w[2] * x1[i] + w[1] * x2[i] + w[0] * x3[i];
    op[i] = f2bf(acc / (1.f + __expf(-acc)));  // silu
  }
  *(ushort4*)(xcb + e) = o;
}

// ---------------------------------------------------------------------------
// Chunked selective scan, thread-per-channel, h[16] in VGPRs.
// gid -> d = gid&2047, c = (gid>>11)&31, b = gid>>16.
// Pass A: from h=0, chunk-final state S[b][c][d][n]; P via exp(a_n * sum(dt)).
// ---------------------------------------------------------------------------
__global__ __launch_bounds__(256) void scan_passA(
    const unsigned short* __restrict__ xzb,
    const unsigned short* __restrict__ xcb,
    const unsigned short* __restrict__ dbl, const void* __restrict__ A_log,
    const int* __restrict__ flag, float* __restrict__ S,
    float* __restrict__ P) {
  const int bf = *flag;
  const int gid = blockIdx.x * 256 + threadIdx.x;
  const int d = gid & (D_INNER - 1);
  const int c = (gid >> 11) & (NCH - 1);
  const int b = gid >> 16;
  float a[16];
#pragma unroll
  for (int n = 0; n < 16; ++n)
    a[n] = -expf(bf ? ld1<true>(A_log, (size_t)d * 16 + n)
                    : ld1<false>(A_log, (size_t)d * 16 + n));
  float h[16] = {};
  float sdt = 0.f;
  const size_t m0 = (size_t)b * SEQ + c * CL;
  for (int t = 0; t < CL; ++t) {
    const size_t m = m0 + t;
    const float dtv = bf2f(xzb[m * 4096 + d]);
    const float xv = bf2f(xcb[m * 2048 + d]);
    const u16x8 B0 = *(const u16x8*)&dbl[m * 128 + 64];
    const u16x8 B1 = *(const u16x8*)&dbl[m * 128 + 72];
    const float dtx = dtv * xv;
    sdt += dtv;
#pragma unroll
    for (int n = 0; n < 16; ++n) {
      const float Bv = bf2f(n < 8 ? B0[n] : B1[n - 8]);
      h[n] = fmaf(__expf(dtv * a[n]), h[n], Bv * dtx);
    }
  }
  const size_t sidx = (((size_t)b * NCH + c) * D_INNER + d) * 16;
#pragma unroll
  for (int n = 0; n < 16; ++n) {
    S[sidx + n] = h[n];
    P[sidx + n] = __expf(a[n] * sdt);
  }
}

// Pass B: serial prefix over NCH chunks; S[c] becomes the INITIAL state of
// chunk c. One thread per (b,d,n) = 131072.
__global__ __launch_bounds__(256) void scan_passB(float* __restrict__ S,
                                                  const float* __restrict__ P) {
  const int idx = blockIdx.x * 256 + threadIdx.x;
  const int n = idx & 15;
  const int d = (idx >> 4) & (D_INNER - 1);
  const int b = idx >> 15;
  float h = 0.f;
#pragma unroll
  for (int c = 0; c < NCH; ++c) {
    const size_t sidx = (((size_t)b * NCH + c) * D_INNER + d) * 16 + n;
    const float s = S[sidx], p = P[sidx];
    S[sidx] = h;  // init for chunk c
    h = p * h + s;
  }
}

// Pass C: replay chunk from true init state; y = (sum_n h*C + D*x)*silu(z).
__global__ __launch_bounds__(256) void scan_passC(
    const unsigned short* __restrict__ xzb,
    const unsigned short* __restrict__ xcb,
    const unsigned short* __restrict__ dbl, const void* __restrict__ A_log,
    const void* __restrict__ Dp, const float* __restrict__ S,
    const int* __restrict__ flag, unsigned short* __restrict__ ybf) {
  const int bf = *flag;
  const int gid = blockIdx.x * 256 + threadIdx.x;
  const int d = gid & (D_INNER - 1);
  const int c = (gid >> 11) & (NCH - 1);
  const int b = gid >> 16;
  float a[16];
#pragma unroll
  for (int n = 0; n < 16; ++n)
    a[n] = -expf(bf ? ld1<true>(A_log, (size_t)d * 16 + n)
                    : ld1<false>(A_log, (size_t)d * 16 + n));
  const float Dv = bf ? ld1<true>(Dp, d) : ld1<false>(Dp, d);
  float h[16];
  const size_t sidx = (((size_t)b * NCH + c) * D_INNER + d) * 16;
#pragma unroll
  for (int n = 0; n < 16; ++n) h[n] = S[sidx + n];
  const size_t m0 = (size_t)b * SEQ + c * CL;
  for (int t = 0; t < CL; ++t) {
    const size_t m = m0 + t;
    const float dtv = bf2f(xzb[m * 4096 + d]);
    const float xv = bf2f(xcb[m * 2048 + d]);
    const u16x8 B0 = *(const u16x8*)&dbl[m * 128 + 64];
    const u16x8 B1 = *(const u16x8*)&dbl[m * 128 + 72];
    const u16x8 C0 = *(const u16x8*)&dbl[m * 128 + 80];
    const u16x8 C1 = *(const u16x8*)&dbl[m * 128 + 88];
    const float dtx = dtv * xv;
    float y = 0.f;
#pragma unroll
    for (int n = 0; n < 16; ++n) {
      const float Bv = bf2f(n < 8 ? B0[n] : B1[n - 8]);
      const float Cv = bf2f(n < 8 ? C0[n] : C1[n - 8]);
      h[n] = fmaf(__expf(dtv * a[n]), h[n], Bv * dtx);
      y = fmaf(h[n], Cv, y);
    }
    const float zv = bf2f(xzb[m * 4096 + 2048 + d]);
    const float yv = y + Dv * xv;
    ybf[m * 2048 + d] = f2bf(yv * (zv / (1.f + __expf(-zv))));
  }
}

// ---------------------------------------------------------------------------
extern "C" void kernel_launch(void* const* d_in, const int* in_sizes, int n_in,
                              void* d_out, int out_size, void* d_ws,
                              size_t ws_size, hipStream_t stream) {
  const void* x = d_in[0];
  const void* in_proj_w = d_in[1];
  const void* conv_w = d_in[2];
  const void* conv_b = d_in[3];
  const void* x_proj_w = d_in[4];
  const void* dt_proj_w = d_in[5];
  const void* dt_proj_b = d_in[6];
  const void* A_log = d_in[7];
  const void* D_param = d_in[8];
  const void* out_proj_w = d_in[9];

  // ws layout (~168 MB):
  // flag 256B | xzb 64MB (ML x 4096 bf16; x-half becomes dt after conv) |
  // xcb 32MB (conv out bf16; pre-conv hosts x_bf 16MB + ipw_bf 8MB) |
  // dbl 2MB (ML x 128 bf16) | ybf 32MB | S 16.8MB | P 16.8MB | opw 4MB |
  // xpw_pad 512KB | dtw 256KB
  char* wsb = (char*)d_ws;
  int* flag = (int*)wsb;
  unsigned short* xzb = (unsigned short*)(wsb + 256);
  unsigned short* xcb = xzb + (size_t)ML * 4096;
  unsigned short* dbl = xcb + (size_t)ML * 2048;
  unsigned short* ybf = dbl + (size_t)ML * 128;
  float* S = (float*)(ybf + (size_t)ML * 2048);
  float* P = S + (size_t)BATCH * NCH * D_INNER * 16;
  unsigned short* opw_bf =
      (unsigned short*)(P + (size_t)BATCH * NCH * D_INNER * 16);
  unsigned short* xpw_pad = opw_bf + (size_t)1024 * 2048;
  unsigned short* dtw_bf = xpw_pad + (size_t)128 * 2048;
  unsigned short* x_bf = xcb;                        // dead after K1
  unsigned short* ipw_bf = xcb + (size_t)ML * 1024;  // dead after K1

  // K0: detect input dtype (fp32 vs bf16)
  detect_kernel<<<1, 256, 0, stream>>>((const unsigned int*)x, flag);
  // conversions
  cvt_kernel<<<(ML * 1024) / 1024, 256, 0, stream>>>(x, x_bf, ML * 1024, flag);
  cvt_kernel<<<(4096 * 1024) / 1024, 256, 0, stream>>>(in_proj_w, ipw_bf,
                                                       4096 * 1024, flag);
  // K1: xz = x @ in_proj_w^T (M=8192,N=4096,K=1024) -> xzb bf16
  {
    dim3 g(4096 / 128, ML / 128);
    gemm_mfma<0><<<g, 256, 0, stream>>>(x_bf, 1024, ipw_bf, 1024, xzb, 4096,
                                        1024, nullptr, flag);
  }
  // K2: causal depthwise conv + SiLU -> xcb bf16 (x_bf/ipw_bf now dead)
  conv_silu_kernel<<<(ML * D_INNER) / 1024, 256, 0, stream>>>(xzb, conv_w,
                                                              conv_b, xcb, flag);
  // weight conversions for the small GEMMs
  cvtpad_kernel<<<(128 * 2048) / 1024, 256, 0, stream>>>(x_proj_w, xpw_pad,
                                                         flag);
  cvt_kernel<<<(2048 * 64) / 1024, 256, 0, stream>>>(dt_proj_w, dtw_bf,
                                                     2048 * 64, flag);
  // K3: dbl = xc @ x_proj_w^T (M=8192, N=128(pad), K=2048) -> bf16, ldc=128
  {
    dim3 g(1, ML / 128);
    gemm_mfma<0><<<g, 256, 0, stream>>>(xcb, 2048, xpw_pad, 2048, dbl, 128,
                                        2048, nullptr, flag);
  }
  // K4: dt = softplus(dbl[:,:64] @ dt_proj_w^T + b) -> xzb x-half (ldc=4096)
  {
    dim3 g(2048 / 128, ML / 128);
    gemm_mfma<2><<<g, 256, 0, stream>>>(dbl, 128, dtw_bf, 64, xzb, 4096, 64,
                                        dt_proj_b, flag);
  }
  // K5: chunked scan (A: chunk states, B: prefix, C: replay + y epilogue)
  scan_passA<<<(BATCH * NCH * D_INNER) / 256, 256, 0, stream>>>(
      xzb, xcb, dbl, A_log, flag, S, P);
  scan_passB<<<(BATCH * D_INNER * 16) / 256, 256, 0, stream>>>(S, P);
  scan_passC<<<(BATCH * NCH * D_INNER) / 256, 256, 0, stream>>>(
      xzb, xcb, dbl, A_log, D_param, S, flag, ybf);
  // K6: out = y @ out_proj_w^T (M=8192,N=1024,K=2048), out dtype per flag
  cvt_kernel<<<(1024 * 2048) / 1024, 256, 0, stream>>>(out_proj_w, opw_bf,
                                                       1024 * 2048, flag);
  {
    dim3 g(1024 / 128, ML / 128);
    gemm_mfma<1><<<g, 256, 0, stream>>>(ybf, 2048, opw_bf, 2048, d_out, 1024,
                                        2048, nullptr, flag);
  }
}

// Round 7
// 572.445 us; speedup vs baseline: 8.3063x; 1.0635x over previous
//
#include <hip/hip_runtime.h>
#include <math.h>

#define D_MODEL 1024
#define D_STATE 16
#define D_CONV 4
#define D_INNER 2048
#define DT_RANK 64
#define BATCH 4
#define SEQ 2048
#define ML (BATCH * SEQ)  // 8192 rows
#define NCH 64            // scan chunks per sequence
#define CL (SEQ / NCH)    // 32 steps per chunk

typedef __attribute__((ext_vector_type(8))) short short8;
typedef __attribute__((ext_vector_type(8))) unsigned short u16x8;
typedef __attribute__((ext_vector_type(4))) float f32x4;

// ---------------------------------------------------------------------------
// dtype helpers: inputs may be fp32 (expected) or bf16 (runtime-detected).
// ---------------------------------------------------------------------------
__device__ __forceinline__ float bf2f(unsigned short u) {
  union { unsigned int i; float f; } v;
  v.i = ((unsigned int)u) << 16;
  return v.f;
}
__device__ __forceinline__ unsigned short f2bf(float f) {
  union { float f; unsigned int i; } u;
  u.f = f;
  unsigned int r = u.i + 0x7fffu + ((u.i >> 16) & 1u);  // RNE
  return (unsigned short)(r >> 16);
}
template <bool BF>
__device__ __forceinline__ float ld1(const void* p, size_t i) {
  if constexpr (BF) return bf2f(((const unsigned short*)p)[i]);
  else return ((const float*)p)[i];
}
template <bool BF>
__device__ __forceinline__ void ld4(const void* p, size_t i, float o[4]) {
  if constexpr (BF) {
    ushort4 v = *(const ushort4*)((const unsigned short*)p + i);
    o[0] = bf2f(v.x); o[1] = bf2f(v.y); o[2] = bf2f(v.z); o[3] = bf2f(v.w);
  } else {
    float4 v = *(const float4*)((const float*)p + i);
    o[0] = v.x; o[1] = v.y; o[2] = v.z; o[3] = v.w;
  }
}

// async global->LDS, 16 B per lane; lds base must be wave-uniform.
__device__ __forceinline__ void gl_lds16(const unsigned short* g,
                                         unsigned short* l) {
  __builtin_amdgcn_global_load_lds(
      (const __attribute__((address_space(1))) void*)g,
      (__attribute__((address_space(3))) void*)l, 16, 0, 0);
}

// ---------------------------------------------------------------------------
// Runtime dtype detection (see R2 notes): flag=1 means bf16 inputs.
// ---------------------------------------------------------------------------
__global__ void detect_kernel(const unsigned int* __restrict__ xw, int* flag) {
  __shared__ int cnt;
  if (threadIdx.x == 0) cnt = 0;
  __syncthreads();
  unsigned int w = xw[threadIdx.x];
  unsigned int e = (w >> 7) & 0xffu;
  if (e < 100u || e > 145u) atomicAdd(&cnt, 1);
  __syncthreads();
  if (threadIdx.x == 0) flag[0] = (cnt < 32) ? 1 : 0;
}

// ---------------------------------------------------------------------------
// Fused conversion of all weights/x to bf16 (one dispatch):
// R0 x (ML*1024) | R1 in_proj_w (4096*1024) | R2 out_proj_w (1024*2048) |
// R3 dt_proj_w (2048*64) | R4 x_proj_w padded 96->128 rows (128*2048)
// ---------------------------------------------------------------------------
#define CVT_N0 (ML * 1024)
#define CVT_N1 (4096 * 1024)
#define CVT_N2 (1024 * 2048)
#define CVT_N3 (2048 * 64)
#define CVT_N4 (128 * 2048)
#define CVT_E0 CVT_N0
#define CVT_E1 (CVT_E0 + CVT_N1)
#define CVT_E2 (CVT_E1 + CVT_N2)
#define CVT_E3 (CVT_E2 + CVT_N3)
#define CVT_E4 (CVT_E3 + CVT_N4)

__device__ __forceinline__ void cvt4(const void* in, size_t i,
                                     unsigned short* out, size_t o, int bf) {
  ushort4 v;
  if (bf) {
    v = *(const ushort4*)((const unsigned short*)in + i);
  } else {
    float4 f = *(const float4*)((const float*)in + i);
    v.x = f2bf(f.x); v.y = f2bf(f.y); v.z = f2bf(f.z); v.w = f2bf(f.w);
  }
  *(ushort4*)(out + o) = v;
}

__global__ __launch_bounds__(256) void cvt_all_kernel(
    const void* __restrict__ x, const void* __restrict__ ipw,
    const void* __restrict__ opw, const void* __restrict__ dtw,
    const void* __restrict__ xpw, unsigned short* __restrict__ x_bf,
    unsigned short* __restrict__ ipw_bf, unsigned short* __restrict__ opw_bf,
    unsigned short* __restrict__ dtw_bf, unsigned short* __restrict__ xpw_pad,
    const int* __restrict__ flag) {
  const int bf = *flag;
  const size_t g = (size_t)(blockIdx.x * 256 + threadIdx.x) * 4;
  if (g < CVT_E0) {
    cvt4(x, g, x_bf, g, bf);
  } else if (g < CVT_E1) {
    const size_t i = g - CVT_E0;
    cvt4(ipw, i, ipw_bf, i, bf);
  } else if (g < CVT_E2) {
    const size_t i = g - CVT_E1;
    cvt4(opw, i, opw_bf, i, bf);
  } else if (g < CVT_E3) {
    const size_t i = g - CVT_E2;
    cvt4(dtw, i, dtw_bf, i, bf);
  } else if (g < CVT_E4) {
    const size_t i = g - CVT_E3;
    const int row = (int)(i >> 11);
    if (row < 96) {
      cvt4(xpw, i, xpw_pad, i, bf);
    } else {
      ushort4 z = {0, 0, 0, 0};
      *(ushort4*)(xpw_pad + i) = z;
    }
  }
}

// ---------------------------------------------------------------------------
// MFMA bf16 GEMM: C[M,N] = A * B^T (+epilogue). A (.,lda) bf16, B (.,ldb)
// bf16, row-major. 128x128 tile, BK=32, 256 thr = 4 waves (2x2), 64x64/wave,
// 16x16x32 MFMA, global_load_lds width-16 staging (m97 structure).
// LDS placement is XOR-swizzled so fragment ds_read_b128 is bank-conflict-
// free: lane l stages global k-chunk ((l&3)^((l>>2)&3)^((l>>4)&3)); the
// fragment for (row, q) lives at slot q^(row&3)^((row>>2)&3).
// EPI 0: store bf16. EPI 1: store per *flag (bf16/fp32). EPI 2: softplus
// (acc + bias[col]) then bf16 store.
// ---------------------------------------------------------------------------
template <int EPI>
__global__ __launch_bounds__(256) void gemm_mfma(
    const unsigned short* __restrict__ A, int lda,
    const unsigned short* __restrict__ B, int ldb, void* __restrict__ C,
    int ldc, int K, const void* __restrict__ bias,
    const int* __restrict__ flag) {
  __shared__ unsigned short As[128 * 32];
  __shared__ unsigned short Bs[128 * 32];
  const int tid = threadIdx.x;
  const int l = tid & 63, w = tid >> 6;
  const int bm = blockIdx.y * 128;
  const int bn = blockIdx.x * 128;
  // staging: lane l of wave w covers row (w*16 + l/4); swizzled k-chunk.
  const int r0 = w * 16 + (l >> 2);
  const int cc = (((l & 3) ^ ((l >> 2) & 3) ^ ((l >> 4) & 3))) * 8;
  const unsigned short* Ap0 = A + (size_t)(bm + r0) * lda + cc;
  const unsigned short* Ap1 = A + (size_t)(bm + r0 + 64) * lda + cc;
  const unsigned short* Bp0 = B + (size_t)(bn + r0) * ldb + cc;
  const unsigned short* Bp1 = B + (size_t)(bn + r0 + 64) * ldb + cc;
  // fragment coords
  const int q = l >> 4, mr = l & 15;
  const int wm = w >> 1, wn = w & 1;
  const int slot = (q ^ (mr & 3) ^ (mr >> 2)) * 8;  // swizzled k-slot
  f32x4 acc[4][4] = {};
  for (int k0 = 0; k0 < K; k0 += 32) {
    gl_lds16(Ap0 + k0, As + w * 512);
    gl_lds16(Ap1 + k0, As + 2048 + w * 512);
    gl_lds16(Bp0 + k0, Bs + w * 512);
    gl_lds16(Bp1 + k0, Bs + 2048 + w * 512);
    __syncthreads();  // drains vmcnt (global_load_lds)
    short8 af[4], bfr[4];
#pragma unroll
    for (int mi = 0; mi < 4; ++mi)
      af[mi] = *(const short8*)&As[(wm * 64 + mi * 16 + mr) * 32 + slot];
#pragma unroll
    for (int ni = 0; ni < 4; ++ni)
      bfr[ni] = *(const short8*)&Bs[(wn * 64 + ni * 16 + mr) * 32 + slot];
#pragma unroll
    for (int mi = 0; mi < 4; ++mi)
#pragma unroll
      for (int ni = 0; ni < 4; ++ni)
        acc[mi][ni] = __builtin_amdgcn_mfma_f32_16x16x32_bf16(
            af[mi], bfr[ni], acc[mi][ni], 0, 0, 0);
    __syncthreads();
  }
  // epilogue: C/D layout col=lane&15, row=(lane>>4)*4+reg  [m89/m91]
  const int bf = *flag;
#pragma unroll
  for (int mi = 0; mi < 4; ++mi) {
#pragma unroll
    for (int ni = 0; ni < 4; ++ni) {
      const int row = bm + wm * 64 + mi * 16 + q * 4;
      const int col = bn + wn * 64 + ni * 16 + mr;
#pragma unroll
      for (int j = 0; j < 4; ++j) {
        float v = acc[mi][ni][j];
        const size_t off = (size_t)(row + j) * ldc + col;
        if (EPI == 2) {
          v += bf ? ld1<true>(bias, col) : ld1<false>(bias, col);
          v = (v > 20.f) ? v : log1pf(expf(v));
          ((unsigned short*)C)[off] = f2bf(v);
        } else if (EPI == 1) {
          if (bf) ((unsigned short*)C)[off] = f2bf(v);
          else ((float*)C)[off] = v;
        } else {
          ((unsigned short*)C)[off] = f2bf(v);
        }
      }
    }
  }
}

// ---------------------------------------------------------------------------
// Depthwise causal conv (width 4) + bias + SiLU, 4 channels per thread.
// xzb: (ML,4096) bf16; x part = cols [0,2048). Output xcb (ML,2048) bf16.
// ---------------------------------------------------------------------------
__global__ __launch_bounds__(256) void conv_silu_kernel(
    const unsigned short* __restrict__ xzb, const void* __restrict__ cw,
    const void* __restrict__ cb, unsigned short* __restrict__ xcb,
    const int* __restrict__ flag) {
  const int bf = *flag;
  const int e = (blockIdx.x * 256 + threadIdx.x) * 4;  // over ML*D_INNER
  const int d = e & (D_INNER - 1);
  const int bl = e >> 11;
  const int l = bl & (SEQ - 1);
  const size_t base = (size_t)bl * 4096 + d;
  float x0[4], x1[4] = {}, x2[4] = {}, x3[4] = {};
  ld4<true>(xzb, base, x0);
  if (l >= 1) ld4<true>(xzb, base - 4096, x1);
  if (l >= 2) ld4<true>(xzb, base - 2 * 4096, x2);
  if (l >= 3) ld4<true>(xzb, base - 3 * 4096, x3);
  ushort4 o;
  unsigned short* op = (unsigned short*)&o;
#pragma unroll
  for (int i = 0; i < 4; ++i) {
    float w[4];
    if (bf) ld4<true>(cw, (size_t)(d + i) * 4, w);
    else ld4<false>(cw, (size_t)(d + i) * 4, w);
    const float bias = bf ? ld1<true>(cb, d + i) : ld1<false>(cb, d + i);
    float acc = bias + w[3] * x0[i] + w[2] * x1[i] + w[1] * x2[i] + w[0] * x3[i];
    op[i] = f2bf(acc / (1.f + __expf(-acc)));  // silu
  }
  *(ushort4*)(xcb + e) = o;
}

// ---------------------------------------------------------------------------
// Chunked selective scan, thread-per-channel, h[16] in VGPRs.
// gid -> d = gid&2047, c = (gid>>11)&(NCH-1), b = gid>>17.
// A_log = log(1..16) broadcast => a_n ~= -(n+1); when that holds (fp32
// world), exp(dt*a_n) = exp(-dt)^(n+1): 1 exp + 15 muls per step instead of
// 16 exps. Runtime-gated; falls back to exact exps otherwise (bf16 world).
// ---------------------------------------------------------------------------
__device__ __forceinline__ void load_a(const void* A_log, int bf, int d,
                                       float a[16], float& dev) {
  float t[4];
#pragma unroll
  for (int k = 0; k < 4; ++k) {
    if (bf) ld4<true>(A_log, (size_t)d * 16 + k * 4, t);
    else ld4<false>(A_log, (size_t)d * 16 + k * 4, t);
#pragma unroll
    for (int j = 0; j < 4; ++j) a[k * 4 + j] = -expf(t[j]);
  }
  dev = 0.f;
#pragma unroll
  for (int n = 0; n < 16; ++n) dev = fmaxf(dev, fabsf(a[n] + (float)(n + 1)));
}

// Pass A: from h=0, chunk-final state S[b][c][d][n]; P via exp(a_n * sum dt).
__global__ __launch_bounds__(256) void scan_passA(
    const unsigned short* __restrict__ xzb,
    const unsigned short* __restrict__ xcb,
    const unsigned short* __restrict__ dbl, const void* __restrict__ A_log,
    const int* __restrict__ flag, float* __restrict__ S,
    float* __restrict__ P) {
  const int bf = *flag;
  const int gid = blockIdx.x * 256 + threadIdx.x;
  const int d = gid & (D_INNER - 1);
  const int c = (gid >> 11) & (NCH - 1);
  const int b = gid >> 17;
  float a[16], dev;
  load_a(A_log, bf, d, a, dev);
  float h[16] = {};
  float sdt = 0.f;
  const size_t m0 = (size_t)b * SEQ + c * CL;
  if (dev < 1e-3f) {  // integer-decay fast path
    for (int t = 0; t < CL; ++t) {
      const size_t m = m0 + t;
      const float dtv = bf2f(xzb[m * 4096 + d]);
      const float xv = bf2f(xcb[m * 2048 + d]);
      const u16x8 B0 = *(const u16x8*)&dbl[m * 128 + 64];
      const u16x8 B1 = *(const u16x8*)&dbl[m * 128 + 72];
      const float dtx = dtv * xv;
      sdt += dtv;
      const float e1 = __expf(-dtv);
      float p = 1.f;
#pragma unroll
      for (int n = 0; n < 16; ++n) {
        const float Bv = bf2f(n < 8 ? B0[n] : B1[n - 8]);
        p *= e1;
        h[n] = fmaf(p, h[n], Bv * dtx);
      }
    }
  } else {
    for (int t = 0; t < CL; ++t) {
      const size_t m = m0 + t;
      const float dtv = bf2f(xzb[m * 4096 + d]);
      const float xv = bf2f(xcb[m * 2048 + d]);
      const u16x8 B0 = *(const u16x8*)&dbl[m * 128 + 64];
      const u16x8 B1 = *(const u16x8*)&dbl[m * 128 + 72];
      const float dtx = dtv * xv;
      sdt += dtv;
#pragma unroll
      for (int n = 0; n < 16; ++n) {
        const float Bv = bf2f(n < 8 ? B0[n] : B1[n - 8]);
        h[n] = fmaf(__expf(dtv * a[n]), h[n], Bv * dtx);
      }
    }
  }
  const size_t sidx = (((size_t)b * NCH + c) * D_INNER + d) * 16;
#pragma unroll
  for (int n = 0; n < 16; ++n) {
    S[sidx + n] = h[n];
    P[sidx + n] = __expf(a[n] * sdt);
  }
}

// Pass B: serial prefix over NCH chunks; S[c] becomes the INITIAL state of
// chunk c. One thread per (b,d,n) = 131072.
__global__ __launch_bounds__(256) void scan_passB(float* __restrict__ S,
                                                  const float* __restrict__ P) {
  const int idx = blockIdx.x * 256 + threadIdx.x;
  const int n = idx & 15;
  const int d = (idx >> 4) & (D_INNER - 1);
  const int b = idx >> 15;
  float h = 0.f;
  for (int c = 0; c < NCH; ++c) {
    const size_t sidx = (((size_t)b * NCH + c) * D_INNER + d) * 16 + n;
    const float s = S[sidx], p = P[sidx];
    S[sidx] = h;  // init for chunk c
    h = p * h + s;
  }
}

// Pass C: replay chunk from true init state; y = (sum_n h*C + D*x)*silu(z).
__global__ __launch_bounds__(256) void scan_passC(
    const unsigned short* __restrict__ xzb,
    const unsigned short* __restrict__ xcb,
    const unsigned short* __restrict__ dbl, const void* __restrict__ A_log,
    const void* __restrict__ Dp, const float* __restrict__ S,
    const int* __restrict__ flag, unsigned short* __restrict__ ybf) {
  const int bf = *flag;
  const int gid = blockIdx.x * 256 + threadIdx.x;
  const int d = gid & (D_INNER - 1);
  const int c = (gid >> 11) & (NCH - 1);
  const int b = gid >> 17;
  float a[16], dev;
  load_a(A_log, bf, d, a, dev);
  const float Dv = bf ? ld1<true>(Dp, d) : ld1<false>(Dp, d);
  float h[16];
  const size_t sidx = (((size_t)b * NCH + c) * D_INNER + d) * 16;
#pragma unroll
  for (int n = 0; n < 16; ++n) h[n] = S[sidx + n];
  const size_t m0 = (size_t)b * SEQ + c * CL;
  const bool trick = dev < 1e-3f;
  for (int t = 0; t < CL; ++t) {
    const size_t m = m0 + t;
    const float dtv = bf2f(xzb[m * 4096 + d]);
    const float xv = bf2f(xcb[m * 2048 + d]);
    const u16x8 B0 = *(const u16x8*)&dbl[m * 128 + 64];
    const u16x8 B1 = *(const u16x8*)&dbl[m * 128 + 72];
    const u16x8 C0 = *(const u16x8*)&dbl[m * 128 + 80];
    const u16x8 C1 = *(const u16x8*)&dbl[m * 128 + 88];
    const float dtx = dtv * xv;
    float y = 0.f;
    if (trick) {
      const float e1 = __expf(-dtv);
      float p = 1.f;
#pragma unroll
      for (int n = 0; n < 16; ++n) {
        const float Bv = bf2f(n < 8 ? B0[n] : B1[n - 8]);
        const float Cv = bf2f(n < 8 ? C0[n] : C1[n - 8]);
        p *= e1;
        h[n] = fmaf(p, h[n], Bv * dtx);
        y = fmaf(h[n], Cv, y);
      }
    } else {
#pragma unroll
      for (int n = 0; n < 16; ++n) {
        const float Bv = bf2f(n < 8 ? B0[n] : B1[n - 8]);
        const float Cv = bf2f(n < 8 ? C0[n] : C1[n - 8]);
        h[n] = fmaf(__expf(dtv * a[n]), h[n], Bv * dtx);
        y = fmaf(h[n], Cv, y);
      }
    }
    const float zv = bf2f(xzb[m * 4096 + 2048 + d]);
    const float yv = y + Dv * xv;
    ybf[m * 2048 + d] = f2bf(yv * (zv / (1.f + __expf(-zv))));
  }
}

// ---------------------------------------------------------------------------
extern "C" void kernel_launch(void* const* d_in, const int* in_sizes, int n_in,
                              void* d_out, int out_size, void* d_ws,
                              size_t ws_size, hipStream_t stream) {
  const void* x = d_in[0];
  const void* in_proj_w = d_in[1];
  const void* conv_w = d_in[2];
  const void* conv_b = d_in[3];
  const void* x_proj_w = d_in[4];
  const void* dt_proj_w = d_in[5];
  const void* dt_proj_b = d_in[6];
  const void* A_log = d_in[7];
  const void* D_param = d_in[8];
  const void* out_proj_w = d_in[9];

  // ws layout (~202 MB; 204.5 MB proven safe in R3):
  // flag 256B | xzb 64MB (ML x 4096 bf16; x-half becomes dt after conv) |
  // xcb 32MB (conv out bf16; pre-conv hosts x_bf 16MB + ipw_bf 8MB) |
  // dbl 2MB (ML x 128 bf16) | ybf 32MB | S 33.5MB | P 33.5MB | opw 4MB |
  // xpw_pad 512KB | dtw 256KB
  char* wsb = (char*)d_ws;
  int* flag = (int*)wsb;
  unsigned short* xzb = (unsigned short*)(wsb + 256);
  unsigned short* xcb = xzb + (size_t)ML * 4096;
  unsigned short* dbl = xcb + (size_t)ML * 2048;
  unsigned short* ybf = dbl + (size_t)ML * 128;
  float* S = (float*)(ybf + (size_t)ML * 2048);
  float* P = S + (size_t)BATCH * NCH * D_INNER * 16;
  unsigned short* opw_bf =
      (unsigned short*)(P + (size_t)BATCH * NCH * D_INNER * 16);
  unsigned short* xpw_pad = opw_bf + (size_t)1024 * 2048;
  unsigned short* dtw_bf = xpw_pad + (size_t)128 * 2048;
  unsigned short* x_bf = xcb;                        // dead after K1
  unsigned short* ipw_bf = xcb + (size_t)ML * 1024;  // dead after K1

  // K0: detect input dtype (fp32 vs bf16)
  detect_kernel<<<1, 256, 0, stream>>>((const unsigned int*)x, flag);
  // fused conversions (x, in_proj_w, out_proj_w, dt_proj_w, x_proj_w-pad)
  cvt_all_kernel<<<CVT_E4 / 1024, 256, 0, stream>>>(
      x, in_proj_w, out_proj_w, dt_proj_w, x_proj_w, x_bf, ipw_bf, opw_bf,
      dtw_bf, xpw_pad, flag);
  // K1: xz = x @ in_proj_w^T (M=8192,N=4096,K=1024) -> xzb bf16
  {
    dim3 g(4096 / 128, ML / 128);
    gemm_mfma<0><<<g, 256, 0, stream>>>(x_bf, 1024, ipw_bf, 1024, xzb, 4096,
                                        1024, nullptr, flag);
  }
  // K2: causal depthwise conv + SiLU -> xcb bf16 (x_bf/ipw_bf now dead)
  conv_silu_kernel<<<(ML * D_INNER) / 1024, 256, 0, stream>>>(xzb, conv_w,
                                                              conv_b, xcb, flag);
  // K3: dbl = xc @ x_proj_w^T (M=8192, N=128(pad), K=2048) -> bf16, ldc=128
  {
    dim3 g(1, ML / 128);
    gemm_mfma<0><<<g, 256, 0, stream>>>(xcb, 2048, xpw_pad, 2048, dbl, 128,
                                        2048, nullptr, flag);
  }
  // K4: dt = softplus(dbl[:,:64] @ dt_proj_w^T + b) -> xzb x-half (ldc=4096)
  {
    dim3 g(2048 / 128, ML / 128);
    gemm_mfma<2><<<g, 256, 0, stream>>>(dbl, 128, dtw_bf, 64, xzb, 4096, 64,
                                        dt_proj_b, flag);
  }
  // K5: chunked scan (A: chunk states, B: prefix, C: replay + y epilogue)
  scan_passA<<<(BATCH * NCH * D_INNER) / 256, 256, 0, stream>>>(
      xzb, xcb, dbl, A_log, flag, S, P);
  scan_passB<<<(BATCH * D_INNER * 16) / 256, 256, 0, stream>>>(S, P);
  scan_passC<<<(BATCH * NCH * D_INNER) / 256, 256, 0, stream>>>(
      xzb, xcb, dbl, A_log, D_param, S, flag, ybf);
  // K6: out = y @ out_proj_w^T (M=8192,N=1024,K=2048), out dtype per flag
  {
    dim3 g(1024 / 128, ML / 128);
    gemm_mfma<1><<<g, 256, 0, stream>>>(ybf, 2048, opw_bf, 2048, d_out, 1024,
                                        2048, nullptr, flag);
  }
}

// Round 8
// 540.602 us; speedup vs baseline: 8.7956x; 1.0589x over previous
//
#include <hip/hip_runtime.h>
#include <hip/hip_bf16.h>
#include <math.h>

#define D_MODEL 1024
#define D_STATE 16
#define D_CONV 4
#define D_INNER 2048
#define DT_RANK 64
#define BATCH 4
#define SEQ 2048
#define ML (BATCH * SEQ)  // 8192 rows
#define NCH 64            // scan chunks per sequence
#define CL (SEQ / NCH)    // 32 steps per chunk

typedef __attribute__((ext_vector_type(8))) short short8;
typedef __attribute__((ext_vector_type(8))) unsigned short u16x8;
typedef __attribute__((ext_vector_type(4))) float f32x4;

// ---------------------------------------------------------------------------
// dtype helpers: inputs may be fp32 (expected) or bf16 (runtime-detected).
// ---------------------------------------------------------------------------
__device__ __forceinline__ float bf2f(unsigned short u) {
  union { unsigned int i; float f; } v;
  v.i = ((unsigned int)u) << 16;
  return v.f;
}
__device__ __forceinline__ unsigned short f2bf(float f) {
  union { float f; unsigned int i; } u;
  u.f = f;
  unsigned int r = u.i + 0x7fffu + ((u.i >> 16) & 1u);  // RNE
  return (unsigned short)(r >> 16);
}
// packed f32x2 -> bf16x2 (v_cvt_pk_bf16_f32 on gfx950); low 16 = a, high = b
__device__ __forceinline__ unsigned int f2bf_pk(float a, float b) {
  union { __hip_bfloat162 h; unsigned int u; } cv;
  cv.h = __float22bfloat162_rn(make_float2(a, b));
  return cv.u;
}
template <bool BF>
__device__ __forceinline__ float ld1(const void* p, size_t i) {
  if constexpr (BF) return bf2f(((const unsigned short*)p)[i]);
  else return ((const float*)p)[i];
}
template <bool BF>
__device__ __forceinline__ void ld4(const void* p, size_t i, float o[4]) {
  if constexpr (BF) {
    ushort4 v = *(const ushort4*)((const unsigned short*)p + i);
    o[0] = bf2f(v.x); o[1] = bf2f(v.y); o[2] = bf2f(v.z); o[3] = bf2f(v.w);
  } else {
    float4 v = *(const float4*)((const float*)p + i);
    o[0] = v.x; o[1] = v.y; o[2] = v.z; o[3] = v.w;
  }
}

// async global->LDS, 16 B per lane; lds base must be wave-uniform.
__device__ __forceinline__ void gl_lds16(const unsigned short* g,
                                         unsigned short* l) {
  __builtin_amdgcn_global_load_lds(
      (const __attribute__((address_space(1))) void*)g,
      (__attribute__((address_space(3))) void*)l, 16, 0, 0);
}

// ---------------------------------------------------------------------------
// Runtime dtype detection (see R2 notes): flag=1 means bf16 inputs.
// ---------------------------------------------------------------------------
__global__ void detect_kernel(const unsigned int* __restrict__ xw, int* flag) {
  __shared__ int cnt;
  if (threadIdx.x == 0) cnt = 0;
  __syncthreads();
  unsigned int w = xw[threadIdx.x];
  unsigned int e = (w >> 7) & 0xffu;
  if (e < 100u || e > 145u) atomicAdd(&cnt, 1);
  __syncthreads();
  if (threadIdx.x == 0) flag[0] = (cnt < 32) ? 1 : 0;
}

// ---------------------------------------------------------------------------
// Fused conversion of all weights/x to bf16 (one dispatch):
// R0 x (ML*1024) | R1 in_proj_w (4096*1024) | R2 out_proj_w (1024*2048) |
// R3 dt_proj_w (2048*64) | R4 x_proj_w padded 96->128 rows (128*2048)
// ---------------------------------------------------------------------------
#define CVT_N0 (ML * 1024)
#define CVT_N1 (4096 * 1024)
#define CVT_N2 (1024 * 2048)
#define CVT_N3 (2048 * 64)
#define CVT_N4 (128 * 2048)
#define CVT_E0 CVT_N0
#define CVT_E1 (CVT_E0 + CVT_N1)
#define CVT_E2 (CVT_E1 + CVT_N2)
#define CVT_E3 (CVT_E2 + CVT_N3)
#define CVT_E4 (CVT_E3 + CVT_N4)

__device__ __forceinline__ void cvt4(const void* in, size_t i,
                                     unsigned short* out, size_t o, int bf) {
  if (bf) {
    *(ushort4*)(out + o) = *(const ushort4*)((const unsigned short*)in + i);
  } else {
    float4 f = *(const float4*)((const float*)in + i);
    uint2 v;
    v.x = f2bf_pk(f.x, f.y);
    v.y = f2bf_pk(f.z, f.w);
    *(uint2*)(out + o) = v;
  }
}

__global__ __launch_bounds__(256) void cvt_all_kernel(
    const void* __restrict__ x, const void* __restrict__ ipw,
    const void* __restrict__ opw, const void* __restrict__ dtw,
    const void* __restrict__ xpw, unsigned short* __restrict__ x_bf,
    unsigned short* __restrict__ ipw_bf, unsigned short* __restrict__ opw_bf,
    unsigned short* __restrict__ dtw_bf, unsigned short* __restrict__ xpw_pad,
    const int* __restrict__ flag) {
  const int bf = *flag;
  const size_t g = (size_t)(blockIdx.x * 256 + threadIdx.x) * 4;
  if (g < CVT_E0) {
    cvt4(x, g, x_bf, g, bf);
  } else if (g < CVT_E1) {
    const size_t i = g - CVT_E0;
    cvt4(ipw, i, ipw_bf, i, bf);
  } else if (g < CVT_E2) {
    const size_t i = g - CVT_E1;
    cvt4(opw, i, opw_bf, i, bf);
  } else if (g < CVT_E3) {
    const size_t i = g - CVT_E2;
    cvt4(dtw, i, dtw_bf, i, bf);
  } else if (g < CVT_E4) {
    const size_t i = g - CVT_E3;
    const int row = (int)(i >> 11);
    if (row < 96) {
      cvt4(xpw, i, xpw_pad, i, bf);
    } else {
      ushort4 z = {0, 0, 0, 0};
      *(ushort4*)(xpw_pad + i) = z;
    }
  }
}

// ---------------------------------------------------------------------------
// MFMA bf16 GEMM: C[M,N] = A * B^T (+epilogue). 128x128 tile, BK=32, 256 thr
// = 4 waves (2x2), 64x64/wave, 16x16x32 MFMA, global_load_lds staging (m97).
// XOR-swizzled LDS (conflict-free ds_read_b128; kept from R7, cost-free).
// EPI 0: store bf16. EPI 1: store per *flag (bf16/fp32). EPI 2: softplus
// (acc + bias[col]) then bf16. EPI 3: split-K partial, f32, slice blockIdx.z.
// TAG distinguishes instantiations in profiles.
// ---------------------------------------------------------------------------
template <int EPI, int TAG>
__global__ __launch_bounds__(256) void gemm_mfma(
    const unsigned short* __restrict__ Ain, int lda,
    const unsigned short* __restrict__ Bin, int ldb, void* __restrict__ C,
    int ldc, int K, const void* __restrict__ bias,
    const int* __restrict__ flag) {
  __shared__ unsigned short As[128 * 32];
  __shared__ unsigned short Bs[128 * 32];
  const unsigned short* A = Ain;
  const unsigned short* B = Bin;
  if (EPI == 3) {  // split-K slice
    A += (size_t)blockIdx.z * 512;
    B += (size_t)blockIdx.z * 512;
  }
  const int tid = threadIdx.x;
  const int l = tid & 63, w = tid >> 6;
  const int bm = blockIdx.y * 128;
  const int bn = blockIdx.x * 128;
  // staging: lane l of wave w covers row (w*16 + l/4); swizzled k-chunk.
  const int r0 = w * 16 + (l >> 2);
  const int cc = (((l & 3) ^ ((l >> 2) & 3) ^ ((l >> 4) & 3))) * 8;
  const unsigned short* Ap0 = A + (size_t)(bm + r0) * lda + cc;
  const unsigned short* Ap1 = A + (size_t)(bm + r0 + 64) * lda + cc;
  const unsigned short* Bp0 = B + (size_t)(bn + r0) * ldb + cc;
  const unsigned short* Bp1 = B + (size_t)(bn + r0 + 64) * ldb + cc;
  // fragment coords
  const int q = l >> 4, mr = l & 15;
  const int wm = w >> 1, wn = w & 1;
  const int slot = (q ^ (mr & 3) ^ (mr >> 2)) * 8;  // swizzled k-slot
  f32x4 acc[4][4] = {};
  for (int k0 = 0; k0 < K; k0 += 32) {
    gl_lds16(Ap0 + k0, As + w * 512);
    gl_lds16(Ap1 + k0, As + 2048 + w * 512);
    gl_lds16(Bp0 + k0, Bs + w * 512);
    gl_lds16(Bp1 + k0, Bs + 2048 + w * 512);
    __syncthreads();  // drains vmcnt (global_load_lds)
    short8 af[4], bfr[4];
#pragma unroll
    for (int mi = 0; mi < 4; ++mi)
      af[mi] = *(const short8*)&As[(wm * 64 + mi * 16 + mr) * 32 + slot];
#pragma unroll
    for (int ni = 0; ni < 4; ++ni)
      bfr[ni] = *(const short8*)&Bs[(wn * 64 + ni * 16 + mr) * 32 + slot];
#pragma unroll
    for (int mi = 0; mi < 4; ++mi)
#pragma unroll
      for (int ni = 0; ni < 4; ++ni)
        acc[mi][ni] = __builtin_amdgcn_mfma_f32_16x16x32_bf16(
            af[mi], bfr[ni], acc[mi][ni], 0, 0, 0);
    __syncthreads();
  }
  // epilogue: C/D layout col=lane&15, row=(lane>>4)*4+reg  [m89/m91]
  const int bf = (EPI == 1 || EPI == 2) ? *flag : 0;
  float* Cp3 = (EPI == 3)
                   ? ((float*)C + (size_t)blockIdx.z * ML * 128)
                   : (float*)C;
#pragma unroll
  for (int mi = 0; mi < 4; ++mi) {
#pragma unroll
    for (int ni = 0; ni < 4; ++ni) {
      const int row = bm + wm * 64 + mi * 16 + q * 4;
      const int col = bn + wn * 64 + ni * 16 + mr;
      const size_t off0 = (size_t)row * ldc + col;
      if (EPI == 0) {
        const unsigned int p01 = f2bf_pk(acc[mi][ni][0], acc[mi][ni][1]);
        const unsigned int p23 = f2bf_pk(acc[mi][ni][2], acc[mi][ni][3]);
        unsigned short* C16 = (unsigned short*)C;
        C16[off0] = (unsigned short)p01;
        C16[off0 + ldc] = (unsigned short)(p01 >> 16);
        C16[off0 + 2 * (size_t)ldc] = (unsigned short)p23;
        C16[off0 + 3 * (size_t)ldc] = (unsigned short)(p23 >> 16);
      } else if (EPI == 3) {
#pragma unroll
        for (int j = 0; j < 4; ++j)
          Cp3[off0 + (size_t)j * ldc] = acc[mi][ni][j];
      } else if (EPI == 2) {
        float v[4];
        const float bv = bf ? ld1<true>(bias, col) : ld1<false>(bias, col);
#pragma unroll
        for (int j = 0; j < 4; ++j) {
          float t = acc[mi][ni][j] + bv;
          v[j] = (t > 20.f) ? t : log1pf(expf(t));
        }
        const unsigned int p01 = f2bf_pk(v[0], v[1]);
        const unsigned int p23 = f2bf_pk(v[2], v[3]);
        unsigned short* C16 = (unsigned short*)C;
        C16[off0] = (unsigned short)p01;
        C16[off0 + ldc] = (unsigned short)(p01 >> 16);
        C16[off0 + 2 * (size_t)ldc] = (unsigned short)p23;
        C16[off0 + 3 * (size_t)ldc] = (unsigned short)(p23 >> 16);
      } else {  // EPI == 1
        if (bf) {
          const unsigned int p01 = f2bf_pk(acc[mi][ni][0], acc[mi][ni][1]);
          const unsigned int p23 = f2bf_pk(acc[mi][ni][2], acc[mi][ni][3]);
          unsigned short* C16 = (unsigned short*)C;
          C16[off0] = (unsigned short)p01;
          C16[off0 + ldc] = (unsigned short)(p01 >> 16);
          C16[off0 + 2 * (size_t)ldc] = (unsigned short)p23;
          C16[off0 + 3 * (size_t)ldc] = (unsigned short)(p23 >> 16);
        } else {
          float* Cf = (float*)C;
#pragma unroll
          for (int j = 0; j < 4; ++j)
            Cf[off0 + (size_t)j * ldc] = acc[mi][ni][j];
        }
      }
    }
  }
}

// Split-K reduce: dbl = bf16(sum of 4 f32 partials). 1M elems, 4/thread.
__global__ __launch_bounds__(256) void reduceK3_kernel(
    const float* __restrict__ part, unsigned short* __restrict__ dbl) {
  const size_t i = (size_t)(blockIdx.x * 256 + threadIdx.x) * 4;
  const size_t st = (size_t)ML * 128;
  float4 a = *(const float4*)(part + i);
  float4 b = *(const float4*)(part + st + i);
  float4 c = *(const float4*)(part + 2 * st + i);
  float4 d = *(const float4*)(part + 3 * st + i);
  uint2 v;
  v.x = f2bf_pk(a.x + b.x + c.x + d.x, a.y + b.y + c.y + d.y);
  v.y = f2bf_pk(a.z + b.z + c.z + d.z, a.w + b.w + c.w + d.w);
  *(uint2*)(dbl + i) = v;
}

// ---------------------------------------------------------------------------
// Depthwise causal conv (width 4) + bias + SiLU, 4 channels per thread.
// xzb: (ML,4096) bf16; x part = cols [0,2048). Output xcb (ML,2048) bf16.
// ---------------------------------------------------------------------------
__global__ __launch_bounds__(256) void conv_silu_kernel(
    const unsigned short* __restrict__ xzb, const void* __restrict__ cw,
    const void* __restrict__ cb, unsigned short* __restrict__ xcb,
    const int* __restrict__ flag) {
  const int bf = *flag;
  const int e = (blockIdx.x * 256 + threadIdx.x) * 4;  // over ML*D_INNER
  const int d = e & (D_INNER - 1);
  const int bl = e >> 11;
  const int l = bl & (SEQ - 1);
  const size_t base = (size_t)bl * 4096 + d;
  float x0[4], x1[4] = {}, x2[4] = {}, x3[4] = {};
  ld4<true>(xzb, base, x0);
  if (l >= 1) ld4<true>(xzb, base - 4096, x1);
  if (l >= 2) ld4<true>(xzb, base - 2 * 4096, x2);
  if (l >= 3) ld4<true>(xzb, base - 3 * 4096, x3);
  float r[4];
#pragma unroll
  for (int i = 0; i < 4; ++i) {
    float w[4];
    if (bf) ld4<true>(cw, (size_t)(d + i) * 4, w);
    else ld4<false>(cw, (size_t)(d + i) * 4, w);
    const float bias = bf ? ld1<true>(cb, d + i) : ld1<false>(cb, d + i);
    float acc = bias + w[3] * x0[i] + w[2] * x1[i] + w[1] * x2[i] + w[0] * x3[i];
    r[i] = acc / (1.f + __expf(-acc));  // silu
  }
  uint2 o;
  o.x = f2bf_pk(r[0], r[1]);
  o.y = f2bf_pk(r[2], r[3]);
  *(uint2*)(xcb + e) = o;
}

// ---------------------------------------------------------------------------
// Chunked selective scan, thread-per-channel, h[16] in VGPRs.
// gid -> d = gid&2047, c = (gid>>11)&(NCH-1), b = gid>>17.
// A_log = log(1..16) broadcast => a_n ~= -(n+1); when that holds (fp32
// world), exp(dt*a_n) = exp(-dt)^(n+1), built as a log-depth power tree
// (R7's serial p*=e1 chain was 16-deep dependent). Runtime-gated; exact-exp
// fallback otherwise (bf16 world).
// ---------------------------------------------------------------------------
__device__ __forceinline__ void load_a(const void* A_log, int bf, int d,
                                       float a[16], float& dev) {
  float t[4];
#pragma unroll
  for (int k = 0; k < 4; ++k) {
    if (bf) ld4<true>(A_log, (size_t)d * 16 + k * 4, t);
    else ld4<false>(A_log, (size_t)d * 16 + k * 4, t);
#pragma unroll
    for (int j = 0; j < 4; ++j) a[k * 4 + j] = -expf(t[j]);
  }
  dev = 0.f;
#pragma unroll
  for (int n = 0; n < 16; ++n) dev = fmaxf(dev, fabsf(a[n] + (float)(n + 1)));
}

// powers pw[n] = e1^(n+1), log-depth tree (max dep ~5)
__device__ __forceinline__ void pow_tree(float e1, float pw[16]) {
  const float e2 = e1 * e1;
  const float e3 = e2 * e1;
  const float e4 = e2 * e2;
  pw[0] = e1; pw[1] = e2; pw[2] = e3; pw[3] = e4;
  pw[4] = e4 * e1; pw[5] = e4 * e2; pw[6] = e4 * e3; pw[7] = e4 * e4;
  const float e8 = pw[7];
  pw[8] = e8 * e1; pw[9] = e8 * e2; pw[10] = e8 * e3; pw[11] = e8 * e4;
  pw[12] = e8 * pw[4]; pw[13] = e8 * pw[5]; pw[14] = e8 * pw[6];
  pw[15] = e8 * e8;
}

// Pass A: from h=0, chunk-final state S[b][c][d][n]; P via exp(a_n * sum dt).
__global__ __launch_bounds__(256) void scan_passA(
    const unsigned short* __restrict__ xzb,
    const unsigned short* __restrict__ xcb,
    const unsigned short* __restrict__ dbl, const void* __restrict__ A_log,
    const int* __restrict__ flag, float* __restrict__ S,
    float* __restrict__ P) {
  const int bf = *flag;
  const int gid = blockIdx.x * 256 + threadIdx.x;
  const int d = gid & (D_INNER - 1);
  const int c = (gid >> 11) & (NCH - 1);
  const int b = gid >> 17;
  float a[16], dev;
  load_a(A_log, bf, d, a, dev);
  float h[16] = {};
  float sdt = 0.f;
  const size_t m0 = (size_t)b * SEQ + c * CL;
  if (dev < 1e-3f) {  // integer-decay fast path
    for (int t = 0; t < CL; ++t) {
      const size_t m = m0 + t;
      const float dtv = bf2f(xzb[m * 4096 + d]);
      const float xv = bf2f(xcb[m * 2048 + d]);
      const u16x8 B0 = *(const u16x8*)&dbl[m * 128 + 64];
      const u16x8 B1 = *(const u16x8*)&dbl[m * 128 + 72];
      const float dtx = dtv * xv;
      sdt += dtv;
      float pw[16];
      pow_tree(__expf(-dtv), pw);
#pragma unroll
      for (int n = 0; n < 16; ++n) {
        const float Bv = bf2f(n < 8 ? B0[n] : B1[n - 8]);
        h[n] = fmaf(pw[n], h[n], Bv * dtx);
      }
    }
  } else {
    for (int t = 0; t < CL; ++t) {
      const size_t m = m0 + t;
      const float dtv = bf2f(xzb[m * 4096 + d]);
      const float xv = bf2f(xcb[m * 2048 + d]);
      const u16x8 B0 = *(const u16x8*)&dbl[m * 128 + 64];
      const u16x8 B1 = *(const u16x8*)&dbl[m * 128 + 72];
      const float dtx = dtv * xv;
      sdt += dtv;
#pragma unroll
      for (int n = 0; n < 16; ++n) {
        const float Bv = bf2f(n < 8 ? B0[n] : B1[n - 8]);
        h[n] = fmaf(__expf(dtv * a[n]), h[n], Bv * dtx);
      }
    }
  }
  const size_t sidx = (((size_t)b * NCH + c) * D_INNER + d) * 16;
#pragma unroll
  for (int n = 0; n < 16; ++n) {
    S[sidx + n] = h[n];
    P[sidx + n] = __expf(a[n] * sdt);
  }
}

// Pass B: serial prefix over NCH chunks; S[c] becomes the INITIAL state of
// chunk c. One thread per (b,d,n) = 131072.
__global__ __launch_bounds__(256) void scan_passB(float* __restrict__ S,
                                                  const float* __restrict__ P) {
  const int idx = blockIdx.x * 256 + threadIdx.x;
  const int n = idx & 15;
  const int d = (idx >> 4) & (D_INNER - 1);
  const int b = idx >> 15;
  float h = 0.f;
  for (int c = 0; c < NCH; ++c) {
    const size_t sidx = (((size_t)b * NCH + c) * D_INNER + d) * 16 + n;
    const float s = S[sidx], p = P[sidx];
    S[sidx] = h;  // init for chunk c
    h = p * h + s;
  }
}

// Pass C: replay chunk from true init state; y = (sum_n h*C + D*x)*silu(z).
__global__ __launch_bounds__(256) void scan_passC(
    const unsigned short* __restrict__ xzb,
    const unsigned short* __restrict__ xcb,
    const unsigned short* __restrict__ dbl, const void* __restrict__ A_log,
    const void* __restrict__ Dp, const float* __restrict__ S,
    const int* __restrict__ flag, unsigned short* __restrict__ ybf) {
  const int bf = *flag;
  const int gid = blockIdx.x * 256 + threadIdx.x;
  const int d = gid & (D_INNER - 1);
  const int c = (gid >> 11) & (NCH - 1);
  const int b = gid >> 17;
  float a[16], dev;
  load_a(A_log, bf, d, a, dev);
  const float Dv = bf ? ld1<true>(Dp, d) : ld1<false>(Dp, d);
  float h[16];
  const size_t sidx = (((size_t)b * NCH + c) * D_INNER + d) * 16;
#pragma unroll
  for (int n = 0; n < 16; ++n) h[n] = S[sidx + n];
  const size_t m0 = (size_t)b * SEQ + c * CL;
  const bool trick = dev < 1e-3f;
  for (int t = 0; t < CL; ++t) {
    const size_t m = m0 + t;
    const float dtv = bf2f(xzb[m * 4096 + d]);
    const float xv = bf2f(xcb[m * 2048 + d]);
    const u16x8 B0 = *(const u16x8*)&dbl[m * 128 + 64];
    const u16x8 B1 = *(const u16x8*)&dbl[m * 128 + 72];
    const u16x8 C0 = *(const u16x8*)&dbl[m * 128 + 80];
    const u16x8 C1 = *(const u16x8*)&dbl[m * 128 + 88];
    const float dtx = dtv * xv;
    float y = 0.f;
    if (trick) {
      float pw[16];
      pow_tree(__expf(-dtv), pw);
#pragma unroll
      for (int n = 0; n < 16; ++n) {
        const float Bv = bf2f(n < 8 ? B0[n] : B1[n - 8]);
        const float Cv = bf2f(n < 8 ? C0[n] : C1[n - 8]);
        h[n] = fmaf(pw[n], h[n], Bv * dtx);
        y = fmaf(h[n], Cv, y);
      }
    } else {
#pragma unroll
      for (int n = 0; n < 16; ++n) {
        const float Bv = bf2f(n < 8 ? B0[n] : B1[n - 8]);
        const float Cv = bf2f(n < 8 ? C0[n] : C1[n - 8]);
        h[n] = fmaf(__expf(dtv * a[n]), h[n], Bv * dtx);
        y = fmaf(h[n], Cv, y);
      }
    }
    const float zv = bf2f(xzb[m * 4096 + 2048 + d]);
    const float yv = y + Dv * xv;
    ybf[m * 2048 + d] = f2bf(yv * (zv / (1.f + __expf(-zv))));
  }
}

// ---------------------------------------------------------------------------
extern "C" void kernel_launch(void* const* d_in, const int* in_sizes, int n_in,
                              void* d_out, int out_size, void* d_ws,
                              size_t ws_size, hipStream_t stream) {
  const void* x = d_in[0];
  const void* in_proj_w = d_in[1];
  const void* conv_w = d_in[2];
  const void* conv_b = d_in[3];
  const void* x_proj_w = d_in[4];
  const void* dt_proj_w = d_in[5];
  const void* dt_proj_b = d_in[6];
  const void* A_log = d_in[7];
  const void* D_param = d_in[8];
  const void* out_proj_w = d_in[9];

  // ws layout (~202 MB):
  // flag 256B | xzb 64MB | xcb 32MB (pre-conv hosts x_bf+ipw_bf) | dbl 2MB |
  // ybf 32MB | S 33.5MB (also hosts K3 split-K partials 16.8MB pre-scan) |
  // P 33.5MB | opw 4MB | xpw_pad 512KB | dtw 256KB
  char* wsb = (char*)d_ws;
  int* flag = (int*)wsb;
  unsigned short* xzb = (unsigned short*)(wsb + 256);
  unsigned short* xcb = xzb + (size_t)ML * 4096;
  unsigned short* dbl = xcb + (size_t)ML * 2048;
  unsigned short* ybf = dbl + (size_t)ML * 128;
  float* S = (float*)(ybf + (size_t)ML * 2048);
  float* P = S + (size_t)BATCH * NCH * D_INNER * 16;
  unsigned short* opw_bf =
      (unsigned short*)(P + (size_t)BATCH * NCH * D_INNER * 16);
  unsigned short* xpw_pad = opw_bf + (size_t)1024 * 2048;
  unsigned short* dtw_bf = xpw_pad + (size_t)128 * 2048;
  unsigned short* x_bf = xcb;                        // dead after K1
  unsigned short* ipw_bf = xcb + (size_t)ML * 1024;  // dead after K1
  float* k3part = S;  // 4 x (ML x 128) f32 partials; dead before scans

  // K0: detect input dtype (fp32 vs bf16)
  detect_kernel<<<1, 256, 0, stream>>>((const unsigned int*)x, flag);
  // fused conversions (x, in_proj_w, out_proj_w, dt_proj_w, x_proj_w-pad)
  cvt_all_kernel<<<CVT_E4 / 1024, 256, 0, stream>>>(
      x, in_proj_w, out_proj_w, dt_proj_w, x_proj_w, x_bf, ipw_bf, opw_bf,
      dtw_bf, xpw_pad, flag);
  // K1: xz = x @ in_proj_w^T (M=8192,N=4096,K=1024) -> xzb bf16
  {
    dim3 g(4096 / 128, ML / 128);
    gemm_mfma<0, 1><<<g, 256, 0, stream>>>(x_bf, 1024, ipw_bf, 1024, xzb,
                                           4096, 1024, nullptr, flag);
  }
  // K2: causal depthwise conv + SiLU -> xcb bf16 (x_bf/ipw_bf now dead)
  conv_silu_kernel<<<(ML * D_INNER) / 1024, 256, 0, stream>>>(
      xzb, conv_w, conv_b, xcb, flag);
  // K3: dbl = xc @ x_proj_w^T (M=8192, N=128(pad), K=2048), split-K x4 ->
  // f32 partials in S region, then reduce+bf16.
  {
    dim3 g(1, ML / 128, 4);
    gemm_mfma<3, 3><<<g, 256, 0, stream>>>(xcb, 2048, xpw_pad, 2048, k3part,
                                           128, 512, nullptr, flag);
  }
  reduceK3_kernel<<<(ML * 128) / 1024, 256, 0, stream>>>(k3part, dbl);
  // K4: dt = softplus(dbl[:,:64] @ dt_proj_w^T + b) -> xzb x-half (ldc=4096)
  {
    dim3 g(2048 / 128, ML / 128);
    gemm_mfma<2, 4><<<g, 256, 0, stream>>>(dbl, 128, dtw_bf, 64, xzb, 4096,
                                           64, dt_proj_b, flag);
  }
  // K5: chunked scan (A: chunk states, B: prefix, C: replay + y epilogue)
  scan_passA<<<(BATCH * NCH * D_INNER) / 256, 256, 0, stream>>>(
      xzb, xcb, dbl, A_log, flag, S, P);
  scan_passB<<<(BATCH * D_INNER * 16) / 256, 256, 0, stream>>>(S, P);
  scan_passC<<<(BATCH * NCH * D_INNER) / 256, 256, 0, stream>>>(
      xzb, xcb, dbl, A_log, D_param, S, flag, ybf);
  // K6: out = y @ out_proj_w^T (M=8192,N=1024,K=2048), out dtype per flag
  {
    dim3 g(1024 / 128, ML / 128);
    gemm_mfma<1, 6><<<g, 256, 0, stream>>>(ybf, 2048, opw_bf, 2048, d_out,
                                           1024, 2048, nullptr, flag);
  }
}